// Round 1
// baseline (1049.603 us; speedup 1.0000x reference)
//
#include <hip/hip_runtime.h>

typedef unsigned short u16;
typedef unsigned int   u32;

#define BT   4096
#define TSEQ 64
#define NB   64

typedef __attribute__((ext_vector_type(8))) short  short8;
typedef __attribute__((ext_vector_type(4))) float  f32x4;
typedef __attribute__((ext_vector_type(2))) _Float16 h2;

__device__ __forceinline__ float bf(u16 v) {
    u32 u = ((u32)v) << 16;
    return __builtin_bit_cast(float, u);
}
__device__ __forceinline__ u16 f2b(float f) {
    u32 u = __builtin_bit_cast(u32, f);
    return (u16)((u + 0x7fffu + ((u >> 16) & 1u)) >> 16);  // RNE
}
__device__ __forceinline__ float lrelu(float x) { return x > 0.f ? x : 0.2f * x; }
__device__ __forceinline__ h2 i2h(int v) { return __builtin_bit_cast(h2, v); }
__device__ __forceinline__ float dot2(int hbits, int wbits, float acc) {
#if __has_builtin(__builtin_amdgcn_fdot2)
    return __builtin_amdgcn_fdot2(i2h(hbits), i2h(wbits), acc, false);
#else
    h2 a = i2h(hbits), b = i2h(wbits);
    return acc + (float)a.x * (float)b.x + (float)a.y * (float)b.y;
#endif
}
__device__ __forceinline__ float fsigm(float x) { return 1.f / (1.f + __expf(-x)); }
__device__ __forceinline__ float ftanh(float x) { return 1.f - 2.f / (__expf(2.f * x) + 1.f); }
__device__ __forceinline__ float ldf(const void* p, int i, int f32) {
    return f32 ? ((const float*)p)[i] : bf(((const u16*)p)[i]);
}
__device__ __forceinline__ u16 ldb(const void* p, int i, int f32) {
    return f32 ? f2b(((const float*)p)[i]) : ((const u16*)p)[i];
}

struct PrepPtrs {
    const void *x, *W1, *b1, *W2, *b2, *W3, *b3, *W4, *b4;
    const void *Wr, *Wk, *Wpim, *Wpir, *Wv;
    const u16* probe;
    u16 *featbf, *PF, *PBk, *PBpim, *PBpir;
    float* scal; int* flag; int* fsync;
};

// pack: each thread packs 8 consecutive k (one octet) for one column ->
// 8 coalesced reads + one contiguous 16B store (old: 2B scatter, ~16x WA)
#define PACK_BLKS 776   // PF 128 | PBk 128 | PBpim 512 | PBpir 8
#define CONV_BLKS 2048  // 2 images per block

// ================= K1: prep = sniff(inline) + pack + conv ===================
__global__ __launch_bounds__(256) void prep_kernel(PrepPtrs P)
{
    const int bid = blockIdx.x, tid = threadIdx.x;
    const int lane = tid & 63;
    u16 pv = P.probe[2 * lane];
    int e = (pv >> 7) & 0xFF;
    unsigned long long m = __ballot(pv == 0 || (e >= 100 && e <= 130));
    const int f32 = (__popcll(m) < 48) ? 1 : 0;

    if (bid == 0) {
        if (tid < 32) P.scal[tid] = 0.f;
        if (tid < 64) P.fsync[tid] = 0;          // LSTM cross-block sync counters
        if (tid == 0) *P.flag = f32;
    }

    if (bid < PACK_BLKS) {
        u16 t8[8];
        if (bid < 128) {                       // PF: Wr -> f16 chunks
            int gid = bid * 256 + tid;         // 32768: (oct, col)
            int col = gid & 1023, oct = gid >> 10;
#pragma unroll
            for (int j = 0; j < 8; j++) {
                float f = ldf(P.Wr, (oct * 8 + j) * 1024 + col, f32);
                _Float16 h = (_Float16)f;
                t8[j] = __builtin_bit_cast(unsigned short, h);
            }
            *(int4*)&P.PF[((size_t)oct * 1024 + col) * 8] = *(int4*)t8;
        } else if (bid < 256) {                // PBk: bf16 B-frag
            int gid = (bid - 128) * 256 + tid;
            int col = gid & 1023, oct = gid >> 10;
#pragma unroll
            for (int j = 0; j < 8; j++) t8[j] = ldb(P.Wk, (oct * 8 + j) * 1024 + col, f32);
            *(int4*)&P.PBk[((((size_t)(oct >> 2) << 10) + col) * 4 + (oct & 3)) * 8] = *(int4*)t8;
        } else if (bid < 768) {                // PBpim
            int gid = (bid - 256) * 256 + tid; // 131072: (oct, col)
            int col = gid & 4095, oct = gid >> 12;
#pragma unroll
            for (int j = 0; j < 8; j++) t8[j] = ldb(P.Wpim, (size_t)(oct * 8 + j) * 4096 + col, f32);
            *(int4*)&P.PBpim[((((size_t)(oct >> 2) << 12) + col) * 4 + (oct & 3)) * 8] = *(int4*)t8;
        } else {                               // PBpir: [pirW|vW|0]
            int gid = (bid - 768) * 256 + tid; // 2048: (oct, col)
            int col = gid & 63, oct = gid >> 6;
#pragma unroll
            for (int j = 0; j < 8; j++) {
                int k = oct * 8 + j;
                u16 v = 0;
                if (col < 36)       v = ldb(P.Wpir, k * 36 + col, f32);
                else if (col == 36) v = ldb(P.Wv, k, f32);
                t8[j] = v;
            }
            *(int4*)&P.PBpir[(((size_t)(oct >> 2) * 64 + col) * 4 + (oct & 3)) * 8] = *(int4*)t8;
        }
        return;
    }

    // ---- conv branch: 2 images per block; LDS-staged bf16 weights ----
    __shared__ __align__(16) u16 wl[19184];
    __shared__ float xs[2][832];
    __shared__ float c1[2][384];
    __shared__ float c2[2][480];
    __shared__ float c3[2][128];
    const int pair = bid - PACK_BLKS;
    const int sub = tid >> 7, stid = tid & 127;
    const int bt = pair * 2 + sub;

    {
        const void* sp[8] = {P.W1, P.b1, P.W2, P.b2, P.W3, P.b3, P.W4, P.b4};
        const int   sn[8] = {512, 16, 2048, 32, 8192, 64, 8192, 128};
        int o = 0;
        for (int s = 0; s < 8; s++) {
            for (int i = tid; i < sn[s]; i += 256) wl[o + i] = ldb(sp[s], i, f32);
            o += sn[s];
        }
    }
    for (int i = stid; i < 832; i += 128) xs[sub][i] = ldf(P.x, bt * 832 + i, f32);
    __syncthreads();

    for (int idx = stid; idx < 96; idx += 128) {
        int pos = idx >> 2, g = idx & 3;
        int oh = pos >> 2, ow = pos & 3;
        float a0 = bf(wl[512 + g * 4]), a1 = bf(wl[513 + g * 4]),
              a2 = bf(wl[514 + g * 4]), a3 = bf(wl[515 + g * 4]);
        for (int kh = 0; kh < 2; kh++)
            for (int kw = 0; kw < 2; kw++)
#pragma unroll
                for (int ic = 0; ic < 8; ic++) {
                    float xv = xs[sub][(2 * oh + kh) * 64 + (2 * ow + kw) * 8 + ic];
                    ushort4 w = *(const ushort4*)&wl[((kh * 2 + kw) * 8 + ic) * 16 + g * 4];
                    a0 += xv * bf(w.x); a1 += xv * bf(w.y);
                    a2 += xv * bf(w.z); a3 += xv * bf(w.w);
                }
        c1[sub][pos * 16 + g * 4]     = lrelu(a0);
        c1[sub][pos * 16 + g * 4 + 1] = lrelu(a1);
        c1[sub][pos * 16 + g * 4 + 2] = lrelu(a2);
        c1[sub][pos * 16 + g * 4 + 3] = lrelu(a3);
    }
    __syncthreads();

    for (int idx = stid; idx < 120; idx += 128) {
        int pos = idx >> 3, g = idx & 7;
        int oh = pos / 3, ow = pos % 3;
        float a0 = bf(wl[2576 + g * 4]), a1 = bf(wl[2577 + g * 4]),
              a2 = bf(wl[2578 + g * 4]), a3 = bf(wl[2579 + g * 4]);
        for (int kh = 0; kh < 2; kh++)
            for (int kw = 0; kw < 2; kw++)
#pragma unroll
                for (int ic = 0; ic < 16; ic++) {
                    float xv = c1[sub][((oh + kh) * 4 + (ow + kw)) * 16 + ic];
                    ushort4 w = *(const ushort4*)&wl[528 + ((kh * 2 + kw) * 16 + ic) * 32 + g * 4];
                    a0 += xv * bf(w.x); a1 += xv * bf(w.y);
                    a2 += xv * bf(w.z); a3 += xv * bf(w.w);
                }
        c2[sub][pos * 32 + g * 4]     = lrelu(a0);
        c2[sub][pos * 32 + g * 4 + 1] = lrelu(a1);
        c2[sub][pos * 32 + g * 4 + 2] = lrelu(a2);
        c2[sub][pos * 32 + g * 4 + 3] = lrelu(a3);
    }
    __syncthreads();

    for (int idx = stid; idx < 32; idx += 128) {
        int oh = idx >> 4, g = idx & 15;
        float a0 = bf(wl[10800 + g * 4]), a1 = bf(wl[10801 + g * 4]),
              a2 = bf(wl[10802 + g * 4]), a3 = bf(wl[10803 + g * 4]);
        for (int kh = 0; kh < 2; kh++)
            for (int kw = 0; kw < 2; kw++)
#pragma unroll
                for (int ic = 0; ic < 32; ic++) {
                    float xv = c2[sub][((2 * oh + kh) * 3 + kw) * 32 + ic];
                    ushort4 w = *(const ushort4*)&wl[2608 + ((kh * 2 + kw) * 32 + ic) * 64 + g * 4];
                    a0 += xv * bf(w.x); a1 += xv * bf(w.y);
                    a2 += xv * bf(w.z); a3 += xv * bf(w.w);
                }
        c3[sub][oh * 64 + g * 4]     = lrelu(a0);
        c3[sub][oh * 64 + g * 4 + 1] = lrelu(a1);
        c3[sub][oh * 64 + g * 4 + 2] = lrelu(a2);
        c3[sub][oh * 64 + g * 4 + 3] = lrelu(a3);
    }
    __syncthreads();

    for (int idx = stid; idx < 64; idx += 128) {
        int oh = idx >> 5, g = idx & 31;
        float a0 = bf(wl[19056 + g * 4]), a1 = bf(wl[19057 + g * 4]),
              a2 = bf(wl[19058 + g * 4]), a3 = bf(wl[19059 + g * 4]);
#pragma unroll
        for (int ic = 0; ic < 64; ic++) {
            float xv = c3[sub][oh * 64 + ic];
            ushort4 w = *(const ushort4*)&wl[10864 + ic * 128 + g * 4];
            a0 += xv * bf(w.x); a1 += xv * bf(w.y);
            a2 += xv * bf(w.z); a3 += xv * bf(w.w);
        }
        P.featbf[bt * 256 + (g * 4 + 0) * 2 + oh] = f2b(lrelu(a0));
        P.featbf[bt * 256 + (g * 4 + 1) * 2 + oh] = f2b(lrelu(a1));
        P.featbf[bt * 256 + (g * 4 + 2) * 2 + oh] = f2b(lrelu(a2));
        P.featbf[bt * 256 + (g * 4 + 3) * 2 + oh] = f2b(lrelu(a3));
    }
}

// ================= K2: zx = featbf @ Wk + b (MFMA) ==========================
__global__ __launch_bounds__(256) void gemm_zx(
    const u16* __restrict__ Abf, const u16* __restrict__ PB,
    const void* __restrict__ bias, const int* __restrict__ flag,
    float* __restrict__ out)
{
    __shared__ __align__(16) u16 As[16 * 264];
    const int mb = blockIdx.y, nb = blockIdx.x, tid = threadIdx.x;
    const int f32 = *flag;
    const int m0 = mb * 16;
    {
        int row = tid >> 4, part = tid & 15;
        const f32x4* src = (const f32x4*)&Abf[(size_t)(m0 + row) * 256 + part * 16];
        f32x4 v0 = src[0], v1 = src[1];
        *(f32x4*)&As[row * 264 + part * 16] = v0;
        *(f32x4*)&As[row * 264 + part * 16 + 8] = v1;
    }
    __syncthreads();
    const int wv = tid >> 6, lane = tid & 63;
    const int colw = lane & 15, q = lane >> 4;
    const int n = nb * 64 + wv * 16 + colw;
    f32x4 acc = {0.f, 0.f, 0.f, 0.f};
#pragma unroll
    for (int kt = 0; kt < 8; kt++) {
        short8 a = *(const short8*)&As[colw * 264 + kt * 32 + q * 8];
        short8 b = *(const short8*)&PB[((((size_t)kt << 10) + n) * 4 + q) * 8];
        acc = __builtin_amdgcn_mfma_f32_16x16x32_bf16(a, b, acc, 0, 0, 0);
    }
    const float bj = ldf(bias, n, f32);
#pragma unroll
    for (int r = 0; r < 4; r++) {
        int row = q * 4 + r;
        out[(size_t)(m0 + row) * 1024 + n] = acc[r] + bj;
    }
}

// ================= K3: LSTM — 4 CUs per sequence, L2 h-exchange =============
// Block (b,p): p in [0,4) owns hidden units [64p,64p+64) of sequence b.
// All weights in registers (16 int4/thread); per-step cross-block exchange of
// the 128B h-slice via agent-scope atomics + per-sequence flag counter.
// bid = p*64 + b (partners share bid%8 -> same-XCD heuristic, correctness
// does not depend on it: AGENT-scope atomics resolve at the coherent point).
__global__ __launch_bounds__(512) void lstm_kernel(
    const float* __restrict__ zx, const u16* __restrict__ PF,
    u16* __restrict__ hseqbf, int* __restrict__ fsync,
    unsigned int* __restrict__ hxg)
{
    __shared__ __align__(16) u16 h16[256];   // full h(t), f16
    __shared__ float zp[512];                // per-column k-half partials
    const int bid = blockIdx.x;
    const int b = bid & 63, p = bid >> 6;
    const int tid = threadIdx.x;
    const int c = tid & 255, khalf = tid >> 8;     // local column, k half
    const int gate = c >> 6, u6 = c & 63;
    const int C = gate * 256 + p * 64 + u6;        // global z column
    const int4* Pw = (const int4*)PF;

    // weight slice: 128 k-values for column C -> 16 int4, all in registers
    int4 w[16];
#pragma unroll
    for (int j = 0; j < 16; j++) w[j] = Pw[(size_t)(khalf * 16 + j) * 1024 + C];

    if (tid < 128) ((unsigned int*)h16)[tid] = 0u;
    float cst = 0.f;                               // cell state (tid<64)
    unsigned int* flagp = (unsigned int*)&fsync[b];
    const size_t zrow0 = (size_t)b * TSEQ * 1024;
    __syncthreads();

    float zxv = (tid < 256) ? zx[zrow0 + C] : 0.f;
    for (int t = 0; t < TSEQ; t++) {
        float a0 = 0.f, a1 = 0.f, a2 = 0.f, a3 = 0.f;
#pragma unroll
        for (int j = 0; j < 16; j++) {
            int4 hv = *(const int4*)&h16[(khalf * 16 + j) * 8];
            a0 = dot2(hv.x, w[j].x, a0);
            a1 = dot2(hv.y, w[j].y, a1);
            a2 = dot2(hv.z, w[j].z, a2);
            a3 = dot2(hv.w, w[j].w, a3);
        }
        zp[tid] = ((a0 + a1) + (a2 + a3)) + zxv;
        __syncthreads();

        // prefetch next-step zx while wave0 runs gates + exchange
        float zxn = 0.f;
        if (tid < 256 && t + 1 < TSEQ) zxn = zx[zrow0 + (size_t)(t + 1) * 1024 + C];

        if (tid < 64) {                            // wave 0: gates for own units
            float ai = zp[tid]       + zp[256 + tid];
            float af = zp[64 + tid]  + zp[320 + tid];
            float ag = zp[128 + tid] + zp[384 + tid];
            float ao = zp[192 + tid] + zp[448 + tid];
            float ig = fsigm(ai), fg = fsigm(af), og = fsigm(ao);
            float gg = ftanh(ag);
            cst = fg * cst + ig * gg;
            float h = og * ftanh(cst);
            u16 hb = __builtin_bit_cast(unsigned short, (_Float16)h);
            hseqbf[(size_t)b * (TSEQ * 256) + t * 256 + p * 64 + tid] = f2b(h);
            // pack lanes (2d,2d+1) -> dword d, publish 32-dword payload
            int hv_ = (int)hb;
            int lo = __shfl(hv_, 2 * tid, 64);
            int hi = __shfl(hv_, 2 * tid + 1, 64);
            if (tid < 32) {
                unsigned int dw = ((unsigned int)lo & 0xffffu) | ((unsigned int)hi << 16);
                __hip_atomic_store(&hxg[(((b * 2 + (t & 1)) * 4 + p) * 32) + tid], dw,
                                   __ATOMIC_RELAXED, __HIP_MEMORY_SCOPE_AGENT);
            }
            __threadfence();
            if (tid == 0) {
                __hip_atomic_fetch_add(flagp, 1u, __ATOMIC_RELEASE,
                                       __HIP_MEMORY_SCOPE_AGENT);
                const unsigned int tgt = 4u * (unsigned int)(t + 1);
                while (__hip_atomic_load(flagp, __ATOMIC_ACQUIRE,
                                         __HIP_MEMORY_SCOPE_AGENT) < tgt)
                    __builtin_amdgcn_s_sleep(1);
            }
        }
        __syncthreads();                           // all 4 parts published
        if (tid < 128) {                           // gather full h(t+1)
            unsigned int dw = __hip_atomic_load(
                &hxg[(size_t)((b * 2 + (t & 1)) * 4) * 32 + tid],
                __ATOMIC_RELAXED, __HIP_MEMORY_SCOPE_AGENT);
            ((unsigned int*)h16)[tid] = dw;
        }
        __syncthreads();
        zxv = zxn;
    }
}

// ================= K4: pir head + vpred (64 blocks) =========================
__global__ __launch_bounds__(256) void pir_kernel(
    const u16* __restrict__ Abf, const u16* __restrict__ PB,
    const void* __restrict__ pir_b, const void* __restrict__ v_b,
    const int* __restrict__ flag, const int* __restrict__ a_taken,
    float* __restrict__ entpir, float* __restrict__ ppira, float* __restrict__ vpred)
{
    __shared__ __align__(16) u16 As[64 * 264];
    const int tid = threadIdx.x;
    const int wv = tid >> 6, lane = tid & 63;
    const int colw = lane & 15, q = lane >> 4;
    const int f32 = *flag;
    const int m0 = blockIdx.x * 64;

    for (int idx = tid; idx < 1024; idx += 256) {
        int row = idx >> 4, part = idx & 15;
        const f32x4* src = (const f32x4*)&Abf[(size_t)(m0 + row) * 256 + part * 16];
        f32x4 v0 = src[0], v1 = src[1];
        *(f32x4*)&As[row * 264 + part * 16] = v0;
        *(f32x4*)&As[row * 264 + part * 16 + 8] = v1;
    }
    __syncthreads();
    f32x4 acc[4];
#pragma unroll
    for (int nt = 0; nt < 4; nt++) acc[nt] = (f32x4){0.f, 0.f, 0.f, 0.f};
#pragma unroll
    for (int kt = 0; kt < 8; kt++) {
        short8 a = *(const short8*)&As[(wv * 16 + colw) * 264 + kt * 32 + q * 8];
#pragma unroll
        for (int nt = 0; nt < 4; nt++) {
            short8 b = *(const short8*)&PB[((((size_t)kt * 64) + nt * 16 + colw) * 4 + q) * 8];
            acc[nt] = __builtin_amdgcn_mfma_f32_16x16x32_bf16(a, b, acc[nt], 0, 0, 0);
        }
    }
    float* zq = (float*)&As[wv * 4224];   // wave-local 16x65 overlay
#pragma unroll
    for (int nt = 0; nt < 4; nt++) {
        int col = nt * 16 + colw;
        float bj = (col < 36) ? ldf(pir_b, col, f32)
                              : (col == 36 ? ldf(v_b, 0, f32) : 0.f);
#pragma unroll
        for (int r = 0; r < 4; r++)
            zq[(q * 4 + r) * 65 + col] = acc[nt][r] + bj;
    }
    if (lane < 16) {
        int R = m0 + wv * 16 + lane;
        const float* zrow = &zq[lane * 65];
        float Z = 0.f, U = 0.f;
        for (int cc = 0; cc < 36; cc++) {
            float z = zrow[cc];
            float ev = __expf(z);
            Z += ev; U += ev * z;
        }
        entpir[R] = logf(Z) - U / Z;
        ppira[R]  = __expf(zrow[a_taken[R]]) / Z;
        vpred[R]  = zrow[36];
    }
}

// ================= K5: pim — M=32 tiles, fused masked-softmax partials ======
__global__ __launch_bounds__(256) void pim_kernel(
    const u16* __restrict__ Abf, const u16* __restrict__ PB,
    const void* __restrict__ pim_b, const int* __restrict__ flag,
    const int* __restrict__ mask, const int* __restrict__ a_taken,
    float* __restrict__ partS, float* __restrict__ partU, float* __restrict__ za)
{
    __shared__ __align__(16) u16 As[32 * 264];   // 16.9 KB
    __shared__ float redS[4][32], redU[4][32];
    const int nb = blockIdx.x, mb = blockIdx.y, tid = threadIdx.x;
    const int wv = tid >> 6, lane = tid & 63;
    const int colw = lane & 15, q = lane >> 4;
    const int f32 = *flag;
    const int m0 = mb * 32;

    for (int idx = tid; idx < 512; idx += 256) {
        int row = idx >> 4, part = idx & 15;
        const f32x4* src = (const f32x4*)&Abf[(size_t)(m0 + row) * 256 + part * 16];
        f32x4 v0 = src[0], v1 = src[1];
        *(f32x4*)&As[row * 264 + part * 16] = v0;
        *(f32x4*)&As[row * 264 + part * 16 + 8] = v1;
    }
    __syncthreads();
    const int n = nb * 64 + wv * 16 + colw;
    f32x4 acc0 = {0.f, 0.f, 0.f, 0.f}, acc1 = {0.f, 0.f, 0.f, 0.f};
#pragma unroll
    for (int kt = 0; kt < 8; kt++) {
        short8 b = *(const short8*)&PB[((((size_t)kt << 12) + n) * 4 + q) * 8];
        short8 a0 = *(const short8*)&As[colw * 264 + kt * 32 + q * 8];
        short8 a1 = *(const short8*)&As[(16 + colw) * 264 + kt * 32 + q * 8];
        acc0 = __builtin_amdgcn_mfma_f32_16x16x32_bf16(a0, b, acc0, 0, 0, 0);
        acc1 = __builtin_amdgcn_mfma_f32_16x16x32_bf16(a1, b, acc1, 0, 0, 0);
    }
    const float bj = ldf(pim_b, n, f32);
#pragma unroll
    for (int half = 0; half < 2; half++) {
        const f32x4& acc = half ? acc1 : acc0;
        float sv[4], uv[4];
#pragma unroll
        for (int r = 0; r < 4; r++) {
            int row = m0 + half * 16 + q * 4 + r;
            float z = acc[r] + bj;
            int mm = mask[(size_t)row * 4096 + n];
            float ev = __expf(z);
            sv[r] = mm ? ev : 0.f;
            uv[r] = mm ? ev * z : 0.f;
            if (n == a_taken[row]) za[row] = z;
        }
#pragma unroll
        for (int r = 0; r < 4; r++) {
            for (int off = 1; off < 16; off <<= 1) {
                sv[r] += __shfl_xor(sv[r], off, 16);
                uv[r] += __shfl_xor(uv[r], off, 16);
            }
            if (colw == 0) {
                redS[wv][half * 16 + q * 4 + r] = sv[r];
                redU[wv][half * 16 + q * 4 + r] = uv[r];
            }
        }
    }
    __syncthreads();
    if (tid < 32) {
        float S = redS[0][tid] + redS[1][tid] + redS[2][tid] + redS[3][tid];
        float U = redU[0][tid] + redU[1][tid] + redU[2][tid] + redU[3][tid];
        partS[(size_t)(m0 + tid) * 64 + nb] = S;
        partU[(size_t)(m0 + tid) * 64 + nb] = U;
    }
}

// ================= K6: tail = pimfin + gae + pg + vf + fin (ticket) =========
#define TAIL_BLOCKS (16 + 256)
__global__ __launch_bounds__(256) void tail_kernel(
    const float* __restrict__ partS, const float* __restrict__ partU,
    const float* __restrict__ za,
    const float* __restrict__ entpir, const float* __restrict__ ppira,
    const float* __restrict__ vpred,
    const void* __restrict__ lgold, const void* __restrict__ gae,
    const void* __restrict__ ovp, const void* __restrict__ ret,
    float* __restrict__ scal, const int* __restrict__ flag,
    void* __restrict__ out)
{
    const int bid = blockIdx.x, tid = threadIdx.x;
    const int f32 = *flag;
    __shared__ float sh[8];
    __shared__ float mst[2];
    if (bid < 16) {
        const int r = bid * 256 + tid;
        float S = 0.f, U = 0.f;
#pragma unroll
        for (int t2 = 0; t2 < 64; t2++) {
            S += partS[(size_t)r * 64 + t2];
            U += partU[(size_t)r * 64 + t2];
        }
        float entpim = logf(S) - U / S;
        float ppima = __expf(za[r]) / S;
        float s = 0.f, s2 = 0.f;
        if (f32) {
            const float* gp = (const float*)gae;
            for (int i = tid; i < BT; i += 256) { float v = gp[i]; s += v; s2 += v * v; }
        } else {
            const u16* gp = (const u16*)gae;
            for (int i = tid; i < BT; i += 256) { float v = bf(gp[i]); s += v; s2 += v * v; }
        }
        for (int off = 32; off; off >>= 1) {
            s += __shfl_down(s, off, 64); s2 += __shfl_down(s2, off, 64);
        }
        if ((tid & 63) == 0) { sh[tid >> 6] = s; sh[4 + (tid >> 6)] = s2; }
        __syncthreads();
        if (tid == 0) {
            float Sa = sh[0] + sh[1] + sh[2] + sh[3];
            float S2a = sh[4] + sh[5] + sh[6] + sh[7];
            float mean = Sa / (float)BT;
            float var = S2a / (float)BT - mean * mean;
            mst[0] = mean; mst[1] = sqrtf(fmaxf(var, 0.f));
        }
        __syncthreads();
        float mean = mst[0], sd = mst[1];
        float p = (r & 1) ? ppima : ppira[r];
        float ln = logf(p);
        float rt = __expf(ln - ldf(lgold, r, f32));
        float g = (ldf(gae, r, f32) - mean) / (sd + 1e-8f);
        float rtc = fminf(fmaxf(rt, 0.8f), 1.2f);
        float pg = fmaxf(-g * rt, -g * rtc);
        float e12 = entpir[r] + entpim;
        for (int off = 32; off; off >>= 1) {
            pg += __shfl_down(pg, off, 64);
            e12 += __shfl_down(e12, off, 64);
        }
        if ((tid & 63) == 0) {
            atomicAdd(&scal[2], pg);
            atomicAdd(&scal[3], e12);
        }
    } else {
        const int i0 = (bid - 16) * 16;
        float s = 0.f;
        if (f32) {
            const float* rp = (const float*)ret;
            const float* op = (const float*)ovp;
            for (int rr = 0; rr < 16; rr++) {
                float vp = vpred[i0 + rr];
                for (int j = tid; j < BT; j += 256) {
                    float r2 = rp[j], o = op[j];
                    float d = fminf(fmaxf(vp - o, -0.2f), 0.2f);
                    float v1 = vp - r2;    v1 *= v1;
                    float v2 = o + d - r2; v2 *= v2;
                    s += fmaxf(v1, v2);
                }
            }
        } else {
            const u16* rp = (const u16*)ret;
            const u16* op = (const u16*)ovp;
            for (int rr = 0; rr < 16; rr++) {
                float vp = vpred[i0 + rr];
                for (int j = tid; j < BT; j += 256) {
                    float r2 = bf(rp[j]), o = bf(op[j]);
                    float d = fminf(fmaxf(vp - o, -0.2f), 0.2f);
                    float v1 = vp - r2;    v1 *= v1;
                    float v2 = o + d - r2; v2 *= v2;
                    s += fmaxf(v1, v2);
                }
            }
        }
        for (int off = 32; off; off >>= 1) s += __shfl_down(s, off, 64);
        if ((tid & 63) == 0) sh[tid >> 6] = s;
        __syncthreads();
        if (tid == 0) atomicAdd(&scal[5], sh[0] + sh[1] + sh[2] + sh[3]);
    }
    __threadfence();
    __syncthreads();
    if (tid == 0) {
        unsigned old = atomicAdd((unsigned int*)&scal[8], 1u);
        if (old == TAIL_BLOCKS - 1) {
            __threadfence();
            float pgs = atomicAdd(&scal[2], 0.f);
            float ents = atomicAdd(&scal[3], 0.f);
            float vfs = atomicAdd(&scal[5], 0.f);
            float pg = pgs / (float)BT;
            float vf = 0.5f * vfs / ((float)BT * (float)BT);
            float loss = pg - ents + vf;
            if (f32) {
                float* o = (float*)out;
                o[0] = loss; o[1] = pg; o[2] = ents; o[3] = vf;
            } else {
                u16* o = (u16*)out;
                o[0] = f2b(loss); o[1] = f2b(pg); o[2] = f2b(ents); o[3] = f2b(vf);
            }
        }
    }
}

extern "C" void kernel_launch(void* const* d_in, const int* in_sizes, int n_in,
                              void* d_out, int out_size, void* d_ws, size_t ws_size,
                              hipStream_t stream)
{
    const int* mask = (const int*)d_in[1];
    const int* a_tk = (const int*)d_in[3];

    float* p = (float*)d_ws;
    u16*   featbf = (u16*)p;            p += 524288;    // 1M u16
    float* zx     = p;                  p += 4194304;   // 16 MB
    u16*   hseqbf = (u16*)p;            p += 524288;    // 1M u16
    u16*   PF     = (u16*)p;            p += 131072;    // f16 Wr
    u16*   PBk    = (u16*)p;            p += 131072;    // bf16 Wk frag
    u16*   PBpim  = (u16*)p;            p += 524288;    // bf16 pimW frag
    u16*   PBpir  = (u16*)p;            p += 8192;      // bf16 [pirW|vW] frag
    float* scal   = p;                  p += 32;
    int*   flag   = (int*)p;            p += 4;
    float* partS  = p;                  p += 262144;
    float* partU  = p;                  p += 262144;
    float* za     = p;                  p += 4096;
    float* entpir = p;                  p += 4096;
    float* ppira  = p;                  p += 4096;
    float* vpred  = p;                  p += 4096;
    int*   fsync  = (int*)p;            p += 64;        // LSTM sync counters
    unsigned int* hxg = (unsigned int*)p; p += 16384;   // h-exchange payload (64KB)

    PrepPtrs P;
    P.x = d_in[0];
    P.W1 = d_in[7];  P.b1 = d_in[8];
    P.W2 = d_in[9];  P.b2 = d_in[10];
    P.W3 = d_in[11]; P.b3 = d_in[12];
    P.W4 = d_in[13]; P.b4 = d_in[14];
    P.Wk = d_in[15]; P.Wr = d_in[16];
    P.Wpir = d_in[18]; P.Wpim = d_in[20]; P.Wv = d_in[22];
    P.probe = (const u16*)d_in[15];
    P.featbf = featbf; P.PF = PF; P.PBk = PBk; P.PBpim = PBpim; P.PBpir = PBpir;
    P.scal = scal; P.flag = flag; P.fsync = fsync;

    prep_kernel<<<PACK_BLKS + CONV_BLKS, 256, 0, stream>>>(P);
    gemm_zx<<<dim3(16, 256), 256, 0, stream>>>(featbf, PBk, d_in[17], flag, zx);
    lstm_kernel<<<256, 512, 0, stream>>>(zx, PF, hseqbf, fsync, hxg);
    pir_kernel<<<64, 256, 0, stream>>>(hseqbf, PBpir, d_in[19], d_in[23], flag,
                                       a_tk, entpir, ppira, vpred);
    pim_kernel<<<dim3(64, 128), 256, 0, stream>>>(hseqbf, PBpim, d_in[21], flag,
                                                  mask, a_tk, partS, partU, za);
    tail_kernel<<<TAIL_BLOCKS, 256, 0, stream>>>(
        partS, partU, za, entpir, ppira, vpred,
        d_in[2], d_in[4], d_in[5], d_in[6], scal, flag, (void*)d_out);
}

// Round 2
// 805.064 us; speedup vs baseline: 1.3038x; 1.3038x over previous
//
#include <hip/hip_runtime.h>

typedef unsigned short u16;
typedef unsigned int   u32;

#define BT   4096
#define TSEQ 64
#define NB   64

typedef __attribute__((ext_vector_type(8))) short  short8;
typedef __attribute__((ext_vector_type(4))) float  f32x4;
typedef __attribute__((ext_vector_type(2))) _Float16 h2;

__device__ __forceinline__ float bf(u16 v) {
    u32 u = ((u32)v) << 16;
    return __builtin_bit_cast(float, u);
}
__device__ __forceinline__ u16 f2b(float f) {
    u32 u = __builtin_bit_cast(u32, f);
    return (u16)((u + 0x7fffu + ((u >> 16) & 1u)) >> 16);  // RNE
}
__device__ __forceinline__ float lrelu(float x) { return x > 0.f ? x : 0.2f * x; }
__device__ __forceinline__ h2 i2h(int v) { return __builtin_bit_cast(h2, v); }
__device__ __forceinline__ float dot2(int hbits, int wbits, float acc) {
#if __has_builtin(__builtin_amdgcn_fdot2)
    return __builtin_amdgcn_fdot2(i2h(hbits), i2h(wbits), acc, false);
#else
    h2 a = i2h(hbits), b = i2h(wbits);
    return acc + (float)a.x * (float)b.x + (float)a.y * (float)b.y;
#endif
}
__device__ __forceinline__ float fsigm(float x) { return 1.f / (1.f + __expf(-x)); }
__device__ __forceinline__ float ftanh(float x) { return 1.f - 2.f / (__expf(2.f * x) + 1.f); }
__device__ __forceinline__ float ldf(const void* p, int i, int f32) {
    return f32 ? ((const float*)p)[i] : bf(((const u16*)p)[i]);
}
__device__ __forceinline__ u16 ldb(const void* p, int i, int f32) {
    return f32 ? f2b(((const float*)p)[i]) : ((const u16*)p)[i];
}

struct PrepPtrs {
    const void *x, *W1, *b1, *W2, *b2, *W3, *b3, *W4, *b4;
    const void *Wr, *Wk, *Wpim, *Wpir, *Wv;
    const u16* probe;
    u16 *featbf, *PF, *PBk, *PBpim, *PBpir;
    float* scal; int* flag;
};

// pack: each thread packs 8 consecutive k (one octet) for one column ->
// 8 coalesced reads + one contiguous 16B store (old: 2B scatter, ~16x WA)
#define PACK_BLKS 776   // PF 128 | PBk 128 | PBpim 512 | PBpir 8
#define CONV_BLKS 2048  // 2 images per block

// ================= K1: prep = sniff(inline) + pack + conv ===================
__global__ __launch_bounds__(256) void prep_kernel(PrepPtrs P)
{
    const int bid = blockIdx.x, tid = threadIdx.x;
    const int lane = tid & 63;
    u16 pv = P.probe[2 * lane];
    int e = (pv >> 7) & 0xFF;
    unsigned long long m = __ballot(pv == 0 || (e >= 100 && e <= 130));
    const int f32 = (__popcll(m) < 48) ? 1 : 0;

    if (bid == 0 && tid < 32) { P.scal[tid] = 0.f; if (tid == 0) *P.flag = f32; }

    if (bid < PACK_BLKS) {
        u16 t8[8];
        if (bid < 128) {                       // PF: Wr -> f16 chunks
            int gid = bid * 256 + tid;         // 32768: (oct, col)
            int col = gid & 1023, oct = gid >> 10;
#pragma unroll
            for (int j = 0; j < 8; j++) {
                float f = ldf(P.Wr, (oct * 8 + j) * 1024 + col, f32);
                _Float16 h = (_Float16)f;
                t8[j] = __builtin_bit_cast(unsigned short, h);
            }
            *(int4*)&P.PF[((size_t)oct * 1024 + col) * 8] = *(int4*)t8;
        } else if (bid < 256) {                // PBk: bf16 B-frag
            int gid = (bid - 128) * 256 + tid;
            int col = gid & 1023, oct = gid >> 10;
#pragma unroll
            for (int j = 0; j < 8; j++) t8[j] = ldb(P.Wk, (oct * 8 + j) * 1024 + col, f32);
            *(int4*)&P.PBk[((((size_t)(oct >> 2) << 10) + col) * 4 + (oct & 3)) * 8] = *(int4*)t8;
        } else if (bid < 768) {                // PBpim
            int gid = (bid - 256) * 256 + tid; // 131072: (oct, col)
            int col = gid & 4095, oct = gid >> 12;
#pragma unroll
            for (int j = 0; j < 8; j++) t8[j] = ldb(P.Wpim, (size_t)(oct * 8 + j) * 4096 + col, f32);
            *(int4*)&P.PBpim[((((size_t)(oct >> 2) << 12) + col) * 4 + (oct & 3)) * 8] = *(int4*)t8;
        } else {                               // PBpir: [pirW|vW|0]
            int gid = (bid - 768) * 256 + tid; // 2048: (oct, col)
            int col = gid & 63, oct = gid >> 6;
#pragma unroll
            for (int j = 0; j < 8; j++) {
                int k = oct * 8 + j;
                u16 v = 0;
                if (col < 36)       v = ldb(P.Wpir, k * 36 + col, f32);
                else if (col == 36) v = ldb(P.Wv, k, f32);
                t8[j] = v;
            }
            *(int4*)&P.PBpir[(((size_t)(oct >> 2) * 64 + col) * 4 + (oct & 3)) * 8] = *(int4*)t8;
        }
        return;
    }

    // ---- conv branch: 2 images per block; LDS-staged bf16 weights ----
    __shared__ __align__(16) u16 wl[19184];
    __shared__ float xs[2][832];
    __shared__ float c1[2][384];
    __shared__ float c2[2][480];
    __shared__ float c3[2][128];
    const int pair = bid - PACK_BLKS;
    const int sub = tid >> 7, stid = tid & 127;
    const int bt = pair * 2 + sub;

    {
        const void* sp[8] = {P.W1, P.b1, P.W2, P.b2, P.W3, P.b3, P.W4, P.b4};
        const int   sn[8] = {512, 16, 2048, 32, 8192, 64, 8192, 128};
        int o = 0;
        for (int s = 0; s < 8; s++) {
            for (int i = tid; i < sn[s]; i += 256) wl[o + i] = ldb(sp[s], i, f32);
            o += sn[s];
        }
    }
    for (int i = stid; i < 832; i += 128) xs[sub][i] = ldf(P.x, bt * 832 + i, f32);
    __syncthreads();

    for (int idx = stid; idx < 96; idx += 128) {
        int pos = idx >> 2, g = idx & 3;
        int oh = pos >> 2, ow = pos & 3;
        float a0 = bf(wl[512 + g * 4]), a1 = bf(wl[513 + g * 4]),
              a2 = bf(wl[514 + g * 4]), a3 = bf(wl[515 + g * 4]);
        for (int kh = 0; kh < 2; kh++)
            for (int kw = 0; kw < 2; kw++)
#pragma unroll
                for (int ic = 0; ic < 8; ic++) {
                    float xv = xs[sub][(2 * oh + kh) * 64 + (2 * ow + kw) * 8 + ic];
                    ushort4 w = *(const ushort4*)&wl[((kh * 2 + kw) * 8 + ic) * 16 + g * 4];
                    a0 += xv * bf(w.x); a1 += xv * bf(w.y);
                    a2 += xv * bf(w.z); a3 += xv * bf(w.w);
                }
        c1[sub][pos * 16 + g * 4]     = lrelu(a0);
        c1[sub][pos * 16 + g * 4 + 1] = lrelu(a1);
        c1[sub][pos * 16 + g * 4 + 2] = lrelu(a2);
        c1[sub][pos * 16 + g * 4 + 3] = lrelu(a3);
    }
    __syncthreads();

    for (int idx = stid; idx < 120; idx += 128) {
        int pos = idx >> 3, g = idx & 7;
        int oh = pos / 3, ow = pos % 3;
        float a0 = bf(wl[2576 + g * 4]), a1 = bf(wl[2577 + g * 4]),
              a2 = bf(wl[2578 + g * 4]), a3 = bf(wl[2579 + g * 4]);
        for (int kh = 0; kh < 2; kh++)
            for (int kw = 0; kw < 2; kw++)
#pragma unroll
                for (int ic = 0; ic < 16; ic++) {
                    float xv = c1[sub][((oh + kh) * 4 + (ow + kw)) * 16 + ic];
                    ushort4 w = *(const ushort4*)&wl[528 + ((kh * 2 + kw) * 16 + ic) * 32 + g * 4];
                    a0 += xv * bf(w.x); a1 += xv * bf(w.y);
                    a2 += xv * bf(w.z); a3 += xv * bf(w.w);
                }
        c2[sub][pos * 32 + g * 4]     = lrelu(a0);
        c2[sub][pos * 32 + g * 4 + 1] = lrelu(a1);
        c2[sub][pos * 32 + g * 4 + 2] = lrelu(a2);
        c2[sub][pos * 32 + g * 4 + 3] = lrelu(a3);
    }
    __syncthreads();

    for (int idx = stid; idx < 32; idx += 128) {
        int oh = idx >> 4, g = idx & 15;
        float a0 = bf(wl[10800 + g * 4]), a1 = bf(wl[10801 + g * 4]),
              a2 = bf(wl[10802 + g * 4]), a3 = bf(wl[10803 + g * 4]);
        for (int kh = 0; kh < 2; kh++)
            for (int kw = 0; kw < 2; kw++)
#pragma unroll
                for (int ic = 0; ic < 32; ic++) {
                    float xv = c2[sub][((2 * oh + kh) * 3 + kw) * 32 + ic];
                    ushort4 w = *(const ushort4*)&wl[2608 + ((kh * 2 + kw) * 32 + ic) * 64 + g * 4];
                    a0 += xv * bf(w.x); a1 += xv * bf(w.y);
                    a2 += xv * bf(w.z); a3 += xv * bf(w.w);
                }
        c3[sub][oh * 64 + g * 4]     = lrelu(a0);
        c3[sub][oh * 64 + g * 4 + 1] = lrelu(a1);
        c3[sub][oh * 64 + g * 4 + 2] = lrelu(a2);
        c3[sub][oh * 64 + g * 4 + 3] = lrelu(a3);
    }
    __syncthreads();

    for (int idx = stid; idx < 64; idx += 128) {
        int oh = idx >> 5, g = idx & 31;
        float a0 = bf(wl[19056 + g * 4]), a1 = bf(wl[19057 + g * 4]),
              a2 = bf(wl[19058 + g * 4]), a3 = bf(wl[19059 + g * 4]);
#pragma unroll
        for (int ic = 0; ic < 64; ic++) {
            float xv = c3[sub][oh * 64 + ic];
            ushort4 w = *(const ushort4*)&wl[10864 + ic * 128 + g * 4];
            a0 += xv * bf(w.x); a1 += xv * bf(w.y);
            a2 += xv * bf(w.z); a3 += xv * bf(w.w);
        }
        P.featbf[bt * 256 + (g * 4 + 0) * 2 + oh] = f2b(lrelu(a0));
        P.featbf[bt * 256 + (g * 4 + 1) * 2 + oh] = f2b(lrelu(a1));
        P.featbf[bt * 256 + (g * 4 + 2) * 2 + oh] = f2b(lrelu(a2));
        P.featbf[bt * 256 + (g * 4 + 3) * 2 + oh] = f2b(lrelu(a3));
    }
}

// ================= K2: zx = featbf @ Wk + b (MFMA) ==========================
__global__ __launch_bounds__(256) void gemm_zx(
    const u16* __restrict__ Abf, const u16* __restrict__ PB,
    const void* __restrict__ bias, const int* __restrict__ flag,
    float* __restrict__ out)
{
    __shared__ __align__(16) u16 As[16 * 264];
    const int mb = blockIdx.y, nb = blockIdx.x, tid = threadIdx.x;
    const int f32 = *flag;
    const int m0 = mb * 16;
    {
        int row = tid >> 4, part = tid & 15;
        const f32x4* src = (const f32x4*)&Abf[(size_t)(m0 + row) * 256 + part * 16];
        f32x4 v0 = src[0], v1 = src[1];
        *(f32x4*)&As[row * 264 + part * 16] = v0;
        *(f32x4*)&As[row * 264 + part * 16 + 8] = v1;
    }
    __syncthreads();
    const int wv = tid >> 6, lane = tid & 63;
    const int colw = lane & 15, q = lane >> 4;
    const int n = nb * 64 + wv * 16 + colw;
    f32x4 acc = {0.f, 0.f, 0.f, 0.f};
#pragma unroll
    for (int kt = 0; kt < 8; kt++) {
        short8 a = *(const short8*)&As[colw * 264 + kt * 32 + q * 8];
        short8 b = *(const short8*)&PB[((((size_t)kt << 10) + n) * 4 + q) * 8];
        acc = __builtin_amdgcn_mfma_f32_16x16x32_bf16(a, b, acc, 0, 0, 0);
    }
    const float bj = ldf(bias, n, f32);
#pragma unroll
    for (int r = 0; r < 4; r++) {
        int row = q * 4 + r;
        out[(size_t)(m0 + row) * 1024 + n] = acc[r] + bj;
    }
}

// ================= K3: LSTM — unit-per-thread, CU-resident weights ==========
// 64 blocks (1/sequence) x 256 threads (1/hidden unit). Thread u computes the
// FULL K=256 dot-products for its 4 gate columns {g*256+u}, so the gate phase
// is exchange-free and all-thread-parallel (no zp LDS, no k-half sum, no idle
// waves). Weights: 24 octets x 4 gates = 96 int4 in VGPRs (384) + 8 octets in
// LDS (128 KB) -> entire Wr CU-resident, zero per-step global weight traffic.
// DS/step: 32 broadcast h-reads + 32 weight reads per thread, 4 waves.
#define NOCT_REG 24
#define NOCT_LDS 8
__global__ __launch_bounds__(256)
__attribute__((amdgpu_waves_per_eu(1, 1)))
void lstm_kernel(
    const float* __restrict__ zx, const u16* __restrict__ PF,
    u16* __restrict__ hseqbf)
{
    __shared__ __align__(16) u16 h16[264];                    // full h(t), f16
    __shared__ __align__(16) int4 wlds[NOCT_LDS * 4 * 256];   // 128 KB
    const int b = blockIdx.x, u = threadIdx.x;
    const int4* Pw = (const int4*)PF;

    // register-resident weight slice: octets 0..23, all 4 gates
    int4 wr[NOCT_REG][4];
#pragma unroll
    for (int o = 0; o < NOCT_REG; o++)
#pragma unroll
        for (int g = 0; g < 4; g++)
            wr[o][g] = Pw[(size_t)o * 1024 + g * 256 + u];
    // LDS-resident: octets 24..31
#pragma unroll
    for (int o = 0; o < NOCT_LDS; o++)
#pragma unroll
        for (int g = 0; g < 4; g++)
            wlds[(o * 4 + g) * 256 + u] = Pw[(size_t)(NOCT_REG + o) * 1024 + g * 256 + u];
    if (u < 128) ((u32*)h16)[u] = 0u;
    float cst = 0.f;
    const size_t z0 = (size_t)b * TSEQ * 1024;
    float zxv0 = zx[z0 + u], zxv1 = zx[z0 + 256 + u],
          zxv2 = zx[z0 + 512 + u], zxv3 = zx[z0 + 768 + u];
    __syncthreads();

    for (int t = 0; t < TSEQ; t++) {
        float ax0 = 0.f, ay0 = 0.f, az0 = 0.f, aw0 = 0.f;
        float ax1 = 0.f, ay1 = 0.f, az1 = 0.f, aw1 = 0.f;
        float ax2 = 0.f, ay2 = 0.f, az2 = 0.f, aw2 = 0.f;
        float ax3 = 0.f, ay3 = 0.f, az3 = 0.f, aw3 = 0.f;
#pragma unroll
        for (int o = 0; o < NOCT_REG; o++) {
            int4 hv = *(const int4*)&h16[o * 8];
            ax0 = dot2(hv.x, wr[o][0].x, ax0); ay0 = dot2(hv.y, wr[o][0].y, ay0);
            az0 = dot2(hv.z, wr[o][0].z, az0); aw0 = dot2(hv.w, wr[o][0].w, aw0);
            ax1 = dot2(hv.x, wr[o][1].x, ax1); ay1 = dot2(hv.y, wr[o][1].y, ay1);
            az1 = dot2(hv.z, wr[o][1].z, az1); aw1 = dot2(hv.w, wr[o][1].w, aw1);
            ax2 = dot2(hv.x, wr[o][2].x, ax2); ay2 = dot2(hv.y, wr[o][2].y, ay2);
            az2 = dot2(hv.z, wr[o][2].z, az2); aw2 = dot2(hv.w, wr[o][2].w, aw2);
            ax3 = dot2(hv.x, wr[o][3].x, ax3); ay3 = dot2(hv.y, wr[o][3].y, ay3);
            az3 = dot2(hv.z, wr[o][3].z, az3); aw3 = dot2(hv.w, wr[o][3].w, aw3);
        }
#pragma unroll
        for (int o = 0; o < NOCT_LDS; o++) {
            int4 hv = *(const int4*)&h16[(NOCT_REG + o) * 8];
            int4 w0 = wlds[(o * 4 + 0) * 256 + u];
            int4 w1 = wlds[(o * 4 + 1) * 256 + u];
            int4 w2 = wlds[(o * 4 + 2) * 256 + u];
            int4 w3 = wlds[(o * 4 + 3) * 256 + u];
            ax0 = dot2(hv.x, w0.x, ax0); ay0 = dot2(hv.y, w0.y, ay0);
            az0 = dot2(hv.z, w0.z, az0); aw0 = dot2(hv.w, w0.w, aw0);
            ax1 = dot2(hv.x, w1.x, ax1); ay1 = dot2(hv.y, w1.y, ay1);
            az1 = dot2(hv.z, w1.z, az1); aw1 = dot2(hv.w, w1.w, aw1);
            ax2 = dot2(hv.x, w2.x, ax2); ay2 = dot2(hv.y, w2.y, ay2);
            az2 = dot2(hv.z, w2.z, az2); aw2 = dot2(hv.w, w2.w, aw2);
            ax3 = dot2(hv.x, w3.x, ax3); ay3 = dot2(hv.y, w3.y, ay3);
            az3 = dot2(hv.z, w3.z, az3); aw3 = dot2(hv.w, w3.w, aw3);
        }
        // prefetch next-step zx while gates run
        float zxn0 = 0.f, zxn1 = 0.f, zxn2 = 0.f, zxn3 = 0.f;
        if (t + 1 < TSEQ) {
            const size_t zr = z0 + (size_t)(t + 1) * 1024;
            zxn0 = zx[zr + u]; zxn1 = zx[zr + 256 + u];
            zxn2 = zx[zr + 512 + u]; zxn3 = zx[zr + 768 + u];
        }
        float zi = ((ax0 + ay0) + (az0 + aw0)) + zxv0;
        float zf = ((ax1 + ay1) + (az1 + aw1)) + zxv1;
        float zg = ((ax2 + ay2) + (az2 + aw2)) + zxv2;
        float zo = ((ax3 + ay3) + (az3 + aw3)) + zxv3;
        float ig = fsigm(zi), fg = fsigm(zf), og = fsigm(zo);
        float gg = ftanh(zg);
        cst = fg * cst + ig * gg;
        float h = og * ftanh(cst);
        __syncthreads();                      // all h16 reads of step t done
        h16[u] = __builtin_bit_cast(unsigned short, (_Float16)h);
        hseqbf[(size_t)b * (TSEQ * 256) + t * 256 + u] = f2b(h);
        __syncthreads();                      // h(t+1) visible
        zxv0 = zxn0; zxv1 = zxn1; zxv2 = zxn2; zxv3 = zxn3;
    }
}

// ================= K4: pir head + vpred (64 blocks) =========================
__global__ __launch_bounds__(256) void pir_kernel(
    const u16* __restrict__ Abf, const u16* __restrict__ PB,
    const void* __restrict__ pir_b, const void* __restrict__ v_b,
    const int* __restrict__ flag, const int* __restrict__ a_taken,
    float* __restrict__ entpir, float* __restrict__ ppira, float* __restrict__ vpred)
{
    __shared__ __align__(16) u16 As[64 * 264];
    const int tid = threadIdx.x;
    const int wv = tid >> 6, lane = tid & 63;
    const int colw = lane & 15, q = lane >> 4;
    const int f32 = *flag;
    const int m0 = blockIdx.x * 64;

    for (int idx = tid; idx < 1024; idx += 256) {
        int row = idx >> 4, part = idx & 15;
        const f32x4* src = (const f32x4*)&Abf[(size_t)(m0 + row) * 256 + part * 16];
        f32x4 v0 = src[0], v1 = src[1];
        *(f32x4*)&As[row * 264 + part * 16] = v0;
        *(f32x4*)&As[row * 264 + part * 16 + 8] = v1;
    }
    __syncthreads();
    f32x4 acc[4];
#pragma unroll
    for (int nt = 0; nt < 4; nt++) acc[nt] = (f32x4){0.f, 0.f, 0.f, 0.f};
#pragma unroll
    for (int kt = 0; kt < 8; kt++) {
        short8 a = *(const short8*)&As[(wv * 16 + colw) * 264 + kt * 32 + q * 8];
#pragma unroll
        for (int nt = 0; nt < 4; nt++) {
            short8 b = *(const short8*)&PB[((((size_t)kt * 64) + nt * 16 + colw) * 4 + q) * 8];
            acc[nt] = __builtin_amdgcn_mfma_f32_16x16x32_bf16(a, b, acc[nt], 0, 0, 0);
        }
    }
    float* zq = (float*)&As[wv * 4224];   // wave-local 16x65 overlay
#pragma unroll
    for (int nt = 0; nt < 4; nt++) {
        int col = nt * 16 + colw;
        float bj = (col < 36) ? ldf(pir_b, col, f32)
                              : (col == 36 ? ldf(v_b, 0, f32) : 0.f);
#pragma unroll
        for (int r = 0; r < 4; r++)
            zq[(q * 4 + r) * 65 + col] = acc[nt][r] + bj;
    }
    if (lane < 16) {
        int R = m0 + wv * 16 + lane;
        const float* zrow = &zq[lane * 65];
        float Z = 0.f, U = 0.f;
        for (int cc = 0; cc < 36; cc++) {
            float z = zrow[cc];
            float ev = __expf(z);
            Z += ev; U += ev * z;
        }
        entpir[R] = logf(Z) - U / Z;
        ppira[R]  = __expf(zrow[a_taken[R]]) / Z;
        vpred[R]  = zrow[36];
    }
}

// ================= K5: pim — M=32 tiles, fused masked-softmax partials ======
__global__ __launch_bounds__(256) void pim_kernel(
    const u16* __restrict__ Abf, const u16* __restrict__ PB,
    const void* __restrict__ pim_b, const int* __restrict__ flag,
    const int* __restrict__ mask, const int* __restrict__ a_taken,
    float* __restrict__ partS, float* __restrict__ partU, float* __restrict__ za)
{
    __shared__ __align__(16) u16 As[32 * 264];   // 16.9 KB
    __shared__ float redS[4][32], redU[4][32];
    const int nb = blockIdx.x, mb = blockIdx.y, tid = threadIdx.x;
    const int wv = tid >> 6, lane = tid & 63;
    const int colw = lane & 15, q = lane >> 4;
    const int f32 = *flag;
    const int m0 = mb * 32;

    for (int idx = tid; idx < 512; idx += 256) {
        int row = idx >> 4, part = idx & 15;
        const f32x4* src = (const f32x4*)&Abf[(size_t)(m0 + row) * 256 + part * 16];
        f32x4 v0 = src[0], v1 = src[1];
        *(f32x4*)&As[row * 264 + part * 16] = v0;
        *(f32x4*)&As[row * 264 + part * 16 + 8] = v1;
    }
    __syncthreads();
    const int n = nb * 64 + wv * 16 + colw;
    f32x4 acc0 = {0.f, 0.f, 0.f, 0.f}, acc1 = {0.f, 0.f, 0.f, 0.f};
#pragma unroll
    for (int kt = 0; kt < 8; kt++) {
        short8 b = *(const short8*)&PB[((((size_t)kt << 12) + n) * 4 + q) * 8];
        short8 a0 = *(const short8*)&As[colw * 264 + kt * 32 + q * 8];
        short8 a1 = *(const short8*)&As[(16 + colw) * 264 + kt * 32 + q * 8];
        acc0 = __builtin_amdgcn_mfma_f32_16x16x32_bf16(a0, b, acc0, 0, 0, 0);
        acc1 = __builtin_amdgcn_mfma_f32_16x16x32_bf16(a1, b, acc1, 0, 0, 0);
    }
    const float bj = ldf(pim_b, n, f32);
#pragma unroll
    for (int half = 0; half < 2; half++) {
        const f32x4& acc = half ? acc1 : acc0;
        float sv[4], uv[4];
#pragma unroll
        for (int r = 0; r < 4; r++) {
            int row = m0 + half * 16 + q * 4 + r;
            float z = acc[r] + bj;
            int mm = mask[(size_t)row * 4096 + n];
            float ev = __expf(z);
            sv[r] = mm ? ev : 0.f;
            uv[r] = mm ? ev * z : 0.f;
            if (n == a_taken[row]) za[row] = z;
        }
#pragma unroll
        for (int r = 0; r < 4; r++) {
            for (int off = 1; off < 16; off <<= 1) {
                sv[r] += __shfl_xor(sv[r], off, 16);
                uv[r] += __shfl_xor(uv[r], off, 16);
            }
            if (colw == 0) {
                redS[wv][half * 16 + q * 4 + r] = sv[r];
                redU[wv][half * 16 + q * 4 + r] = uv[r];
            }
        }
    }
    __syncthreads();
    if (tid < 32) {
        float S = redS[0][tid] + redS[1][tid] + redS[2][tid] + redS[3][tid];
        float U = redU[0][tid] + redU[1][tid] + redU[2][tid] + redU[3][tid];
        partS[(size_t)(m0 + tid) * 64 + nb] = S;
        partU[(size_t)(m0 + tid) * 64 + nb] = U;
    }
}

// ================= K6: tail = pimfin + gae + pg + vf + fin (ticket) =========
#define TAIL_BLOCKS (16 + 256)
__global__ __launch_bounds__(256) void tail_kernel(
    const float* __restrict__ partS, const float* __restrict__ partU,
    const float* __restrict__ za,
    const float* __restrict__ entpir, const float* __restrict__ ppira,
    const float* __restrict__ vpred,
    const void* __restrict__ lgold, const void* __restrict__ gae,
    const void* __restrict__ ovp, const void* __restrict__ ret,
    float* __restrict__ scal, const int* __restrict__ flag,
    void* __restrict__ out)
{
    const int bid = blockIdx.x, tid = threadIdx.x;
    const int f32 = *flag;
    __shared__ float sh[8];
    __shared__ float mst[2];
    if (bid < 16) {
        const int r = bid * 256 + tid;
        float S = 0.f, U = 0.f;
#pragma unroll
        for (int t2 = 0; t2 < 64; t2++) {
            S += partS[(size_t)r * 64 + t2];
            U += partU[(size_t)r * 64 + t2];
        }
        float entpim = logf(S) - U / S;
        float ppima = __expf(za[r]) / S;
        float s = 0.f, s2 = 0.f;
        if (f32) {
            const float* gp = (const float*)gae;
            for (int i = tid; i < BT; i += 256) { float v = gp[i]; s += v; s2 += v * v; }
        } else {
            const u16* gp = (const u16*)gae;
            for (int i = tid; i < BT; i += 256) { float v = bf(gp[i]); s += v; s2 += v * v; }
        }
        for (int off = 32; off; off >>= 1) {
            s += __shfl_down(s, off, 64); s2 += __shfl_down(s2, off, 64);
        }
        if ((tid & 63) == 0) { sh[tid >> 6] = s; sh[4 + (tid >> 6)] = s2; }
        __syncthreads();
        if (tid == 0) {
            float Sa = sh[0] + sh[1] + sh[2] + sh[3];
            float S2a = sh[4] + sh[5] + sh[6] + sh[7];
            float mean = Sa / (float)BT;
            float var = S2a / (float)BT - mean * mean;
            mst[0] = mean; mst[1] = sqrtf(fmaxf(var, 0.f));
        }
        __syncthreads();
        float mean = mst[0], sd = mst[1];
        float p = (r & 1) ? ppima : ppira[r];
        float ln = logf(p);
        float rt = __expf(ln - ldf(lgold, r, f32));
        float g = (ldf(gae, r, f32) - mean) / (sd + 1e-8f);
        float rtc = fminf(fmaxf(rt, 0.8f), 1.2f);
        float pg = fmaxf(-g * rt, -g * rtc);
        float e12 = entpir[r] + entpim;
        for (int off = 32; off; off >>= 1) {
            pg += __shfl_down(pg, off, 64);
            e12 += __shfl_down(e12, off, 64);
        }
        if ((tid & 63) == 0) {
            atomicAdd(&scal[2], pg);
            atomicAdd(&scal[3], e12);
        }
    } else {
        const int i0 = (bid - 16) * 16;
        float s = 0.f;
        if (f32) {
            const float* rp = (const float*)ret;
            const float* op = (const float*)ovp;
            for (int rr = 0; rr < 16; rr++) {
                float vp = vpred[i0 + rr];
                for (int j = tid; j < BT; j += 256) {
                    float r2 = rp[j], o = op[j];
                    float d = fminf(fmaxf(vp - o, -0.2f), 0.2f);
                    float v1 = vp - r2;    v1 *= v1;
                    float v2 = o + d - r2; v2 *= v2;
                    s += fmaxf(v1, v2);
                }
            }
        } else {
            const u16* rp = (const u16*)ret;
            const u16* op = (const u16*)ovp;
            for (int rr = 0; rr < 16; rr++) {
                float vp = vpred[i0 + rr];
                for (int j = tid; j < BT; j += 256) {
                    float r2 = bf(rp[j]), o = bf(op[j]);
                    float d = fminf(fmaxf(vp - o, -0.2f), 0.2f);
                    float v1 = vp - r2;    v1 *= v1;
                    float v2 = o + d - r2; v2 *= v2;
                    s += fmaxf(v1, v2);
                }
            }
        }
        for (int off = 32; off; off >>= 1) s += __shfl_down(s, off, 64);
        if ((tid & 63) == 0) sh[tid >> 6] = s;
        __syncthreads();
        if (tid == 0) atomicAdd(&scal[5], sh[0] + sh[1] + sh[2] + sh[3]);
    }
    __threadfence();
    __syncthreads();
    if (tid == 0) {
        unsigned old = atomicAdd((unsigned int*)&scal[8], 1u);
        if (old == TAIL_BLOCKS - 1) {
            __threadfence();
            float pgs = atomicAdd(&scal[2], 0.f);
            float ents = atomicAdd(&scal[3], 0.f);
            float vfs = atomicAdd(&scal[5], 0.f);
            float pg = pgs / (float)BT;
            float vf = 0.5f * vfs / ((float)BT * (float)BT);
            float loss = pg - ents + vf;
            if (f32) {
                float* o = (float*)out;
                o[0] = loss; o[1] = pg; o[2] = ents; o[3] = vf;
            } else {
                u16* o = (u16*)out;
                o[0] = f2b(loss); o[1] = f2b(pg); o[2] = f2b(ents); o[3] = f2b(vf);
            }
        }
    }
}

extern "C" void kernel_launch(void* const* d_in, const int* in_sizes, int n_in,
                              void* d_out, int out_size, void* d_ws, size_t ws_size,
                              hipStream_t stream)
{
    const int* mask = (const int*)d_in[1];
    const int* a_tk = (const int*)d_in[3];

    float* p = (float*)d_ws;
    u16*   featbf = (u16*)p;            p += 524288;    // 1M u16
    float* zx     = p;                  p += 4194304;   // 16 MB
    u16*   hseqbf = (u16*)p;            p += 524288;    // 1M u16
    u16*   PF     = (u16*)p;            p += 131072;    // f16 Wr
    u16*   PBk    = (u16*)p;            p += 131072;    // bf16 Wk frag
    u16*   PBpim  = (u16*)p;            p += 524288;    // bf16 pimW frag
    u16*   PBpir  = (u16*)p;            p += 8192;      // bf16 [pirW|vW] frag
    float* scal   = p;                  p += 32;
    int*   flag   = (int*)p;            p += 4;
    float* partS  = p;                  p += 262144;
    float* partU  = p;                  p += 262144;
    float* za     = p;                  p += 4096;
    float* entpir = p;                  p += 4096;
    float* ppira  = p;                  p += 4096;
    float* vpred  = p;                  p += 4096;

    PrepPtrs P;
    P.x = d_in[0];
    P.W1 = d_in[7];  P.b1 = d_in[8];
    P.W2 = d_in[9];  P.b2 = d_in[10];
    P.W3 = d_in[11]; P.b3 = d_in[12];
    P.W4 = d_in[13]; P.b4 = d_in[14];
    P.Wk = d_in[15]; P.Wr = d_in[16];
    P.Wpir = d_in[18]; P.Wpim = d_in[20]; P.Wv = d_in[22];
    P.probe = (const u16*)d_in[15];
    P.featbf = featbf; P.PF = PF; P.PBk = PBk; P.PBpim = PBpim; P.PBpir = PBpir;
    P.scal = scal; P.flag = flag;

    prep_kernel<<<PACK_BLKS + CONV_BLKS, 256, 0, stream>>>(P);
    gemm_zx<<<dim3(16, 256), 256, 0, stream>>>(featbf, PBk, d_in[17], flag, zx);
    lstm_kernel<<<NB, 256, 0, stream>>>(zx, PF, hseqbf);
    pir_kernel<<<64, 256, 0, stream>>>(hseqbf, PBpir, d_in[19], d_in[23], flag,
                                       a_tk, entpir, ppira, vpred);
    pim_kernel<<<dim3(64, 128), 256, 0, stream>>>(hseqbf, PBpim, d_in[21], flag,
                                                  mask, a_tk, partS, partU, za);
    tail_kernel<<<TAIL_BLOCKS, 256, 0, stream>>>(
        partS, partU, za, entpir, ppira, vpred,
        d_in[2], d_in[4], d_in[5], d_in[6], scal, flag, (void*)d_out);
}

// Round 3
// 454.736 us; speedup vs baseline: 2.3082x; 1.7704x over previous
//
#include <hip/hip_runtime.h>

typedef unsigned short u16;
typedef unsigned int   u32;

#define BT   4096
#define TSEQ 64
#define NB   64

typedef __attribute__((ext_vector_type(8))) short  short8;
typedef __attribute__((ext_vector_type(4))) float  f32x4;
typedef __attribute__((ext_vector_type(2))) _Float16 h2;

__device__ __forceinline__ float bf(u16 v) {
    u32 u = ((u32)v) << 16;
    return __builtin_bit_cast(float, u);
}
__device__ __forceinline__ u16 f2b(float f) {
    u32 u = __builtin_bit_cast(u32, f);
    return (u16)((u + 0x7fffu + ((u >> 16) & 1u)) >> 16);  // RNE
}
__device__ __forceinline__ float lrelu(float x) { return x > 0.f ? x : 0.2f * x; }
__device__ __forceinline__ h2 i2h(int v) { return __builtin_bit_cast(h2, v); }
__device__ __forceinline__ float dot2(int hbits, int wbits, float acc) {
#if __has_builtin(__builtin_amdgcn_fdot2)
    return __builtin_amdgcn_fdot2(i2h(hbits), i2h(wbits), acc, false);
#else
    h2 a = i2h(hbits), b = i2h(wbits);
    return acc + (float)a.x * (float)b.x + (float)a.y * (float)b.y;
#endif
}
__device__ __forceinline__ float fsigm(float x) { return 1.f / (1.f + __expf(-x)); }
__device__ __forceinline__ float ftanh(float x) { return 1.f - 2.f / (__expf(2.f * x) + 1.f); }
__device__ __forceinline__ float ldf(const void* p, int i, int f32) {
    return f32 ? ((const float*)p)[i] : bf(((const u16*)p)[i]);
}
__device__ __forceinline__ u16 ldb(const void* p, int i, int f32) {
    return f32 ? f2b(((const float*)p)[i]) : ((const u16*)p)[i];
}

struct PrepPtrs {
    const void *x, *W1, *b1, *W2, *b2, *W3, *b3, *W4, *b4;
    const void *Wr, *Wk, *Wpim, *Wpir, *Wv;
    const u16* probe;
    u16 *featbf, *PF, *PBk, *PBpim, *PBpir;
    float* scal; int* flag;
};

// pack: each thread packs 8 consecutive k (one octet) for one column ->
// 8 coalesced reads + one contiguous 16B store (old: 2B scatter, ~16x WA)
#define PACK_BLKS 776   // PF 128 | PBk 128 | PBpim 512 | PBpir 8
#define CONV_BLKS 2048  // 2 images per block

// ================= K1: prep = sniff(inline) + pack + conv ===================
__global__ __launch_bounds__(256) void prep_kernel(PrepPtrs P)
{
    const int bid = blockIdx.x, tid = threadIdx.x;
    const int lane = tid & 63;
    u16 pv = P.probe[2 * lane];
    int e = (pv >> 7) & 0xFF;
    unsigned long long m = __ballot(pv == 0 || (e >= 100 && e <= 130));
    const int f32 = (__popcll(m) < 48) ? 1 : 0;

    if (bid == 0 && tid < 32) { P.scal[tid] = 0.f; if (tid == 0) *P.flag = f32; }

    if (bid < PACK_BLKS) {
        u16 t8[8];
        if (bid < 128) {                       // PF: Wr -> f16 chunks
            int gid = bid * 256 + tid;         // 32768: (oct, col)
            int col = gid & 1023, oct = gid >> 10;
#pragma unroll
            for (int j = 0; j < 8; j++) {
                float f = ldf(P.Wr, (oct * 8 + j) * 1024 + col, f32);
                _Float16 h = (_Float16)f;
                t8[j] = __builtin_bit_cast(unsigned short, h);
            }
            *(int4*)&P.PF[((size_t)oct * 1024 + col) * 8] = *(int4*)t8;
        } else if (bid < 256) {                // PBk: bf16 B-frag
            int gid = (bid - 128) * 256 + tid;
            int col = gid & 1023, oct = gid >> 10;
#pragma unroll
            for (int j = 0; j < 8; j++) t8[j] = ldb(P.Wk, (oct * 8 + j) * 1024 + col, f32);
            *(int4*)&P.PBk[((((size_t)(oct >> 2) << 10) + col) * 4 + (oct & 3)) * 8] = *(int4*)t8;
        } else if (bid < 768) {                // PBpim
            int gid = (bid - 256) * 256 + tid; // 131072: (oct, col)
            int col = gid & 4095, oct = gid >> 12;
#pragma unroll
            for (int j = 0; j < 8; j++) t8[j] = ldb(P.Wpim, (size_t)(oct * 8 + j) * 4096 + col, f32);
            *(int4*)&P.PBpim[((((size_t)(oct >> 2) << 12) + col) * 4 + (oct & 3)) * 8] = *(int4*)t8;
        } else {                               // PBpir: [pirW|vW|0]
            int gid = (bid - 768) * 256 + tid; // 2048: (oct, col)
            int col = gid & 63, oct = gid >> 6;
#pragma unroll
            for (int j = 0; j < 8; j++) {
                int k = oct * 8 + j;
                u16 v = 0;
                if (col < 36)       v = ldb(P.Wpir, k * 36 + col, f32);
                else if (col == 36) v = ldb(P.Wv, k, f32);
                t8[j] = v;
            }
            *(int4*)&P.PBpir[(((size_t)(oct >> 2) * 64 + col) * 4 + (oct & 3)) * 8] = *(int4*)t8;
        }
        return;
    }

    // ---- conv branch: 2 images per block; LDS-staged bf16 weights ----
    __shared__ __align__(16) u16 wl[19184];
    __shared__ float xs[2][832];
    __shared__ float c1[2][384];
    __shared__ float c2[2][480];
    __shared__ float c3[2][128];
    const int pair = bid - PACK_BLKS;
    const int sub = tid >> 7, stid = tid & 127;
    const int bt = pair * 2 + sub;

    {
        const void* sp[8] = {P.W1, P.b1, P.W2, P.b2, P.W3, P.b3, P.W4, P.b4};
        const int   sn[8] = {512, 16, 2048, 32, 8192, 64, 8192, 128};
        int o = 0;
        for (int s = 0; s < 8; s++) {
            for (int i = tid; i < sn[s]; i += 256) wl[o + i] = ldb(sp[s], i, f32);
            o += sn[s];
        }
    }
    for (int i = stid; i < 832; i += 128) xs[sub][i] = ldf(P.x, bt * 832 + i, f32);
    __syncthreads();

    for (int idx = stid; idx < 96; idx += 128) {
        int pos = idx >> 2, g = idx & 3;
        int oh = pos >> 2, ow = pos & 3;
        float a0 = bf(wl[512 + g * 4]), a1 = bf(wl[513 + g * 4]),
              a2 = bf(wl[514 + g * 4]), a3 = bf(wl[515 + g * 4]);
        for (int kh = 0; kh < 2; kh++)
            for (int kw = 0; kw < 2; kw++)
#pragma unroll
                for (int ic = 0; ic < 8; ic++) {
                    float xv = xs[sub][(2 * oh + kh) * 64 + (2 * ow + kw) * 8 + ic];
                    ushort4 w = *(const ushort4*)&wl[((kh * 2 + kw) * 8 + ic) * 16 + g * 4];
                    a0 += xv * bf(w.x); a1 += xv * bf(w.y);
                    a2 += xv * bf(w.z); a3 += xv * bf(w.w);
                }
        c1[sub][pos * 16 + g * 4]     = lrelu(a0);
        c1[sub][pos * 16 + g * 4 + 1] = lrelu(a1);
        c1[sub][pos * 16 + g * 4 + 2] = lrelu(a2);
        c1[sub][pos * 16 + g * 4 + 3] = lrelu(a3);
    }
    __syncthreads();

    for (int idx = stid; idx < 120; idx += 128) {
        int pos = idx >> 3, g = idx & 7;
        int oh = pos / 3, ow = pos % 3;
        float a0 = bf(wl[2576 + g * 4]), a1 = bf(wl[2577 + g * 4]),
              a2 = bf(wl[2578 + g * 4]), a3 = bf(wl[2579 + g * 4]);
        for (int kh = 0; kh < 2; kh++)
            for (int kw = 0; kw < 2; kw++)
#pragma unroll
                for (int ic = 0; ic < 16; ic++) {
                    float xv = c1[sub][((oh + kh) * 4 + (ow + kw)) * 16 + ic];
                    ushort4 w = *(const ushort4*)&wl[528 + ((kh * 2 + kw) * 16 + ic) * 32 + g * 4];
                    a0 += xv * bf(w.x); a1 += xv * bf(w.y);
                    a2 += xv * bf(w.z); a3 += xv * bf(w.w);
                }
        c2[sub][pos * 32 + g * 4]     = lrelu(a0);
        c2[sub][pos * 32 + g * 4 + 1] = lrelu(a1);
        c2[sub][pos * 32 + g * 4 + 2] = lrelu(a2);
        c2[sub][pos * 32 + g * 4 + 3] = lrelu(a3);
    }
    __syncthreads();

    for (int idx = stid; idx < 32; idx += 128) {
        int oh = idx >> 4, g = idx & 15;
        float a0 = bf(wl[10800 + g * 4]), a1 = bf(wl[10801 + g * 4]),
              a2 = bf(wl[10802 + g * 4]), a3 = bf(wl[10803 + g * 4]);
        for (int kh = 0; kh < 2; kh++)
            for (int kw = 0; kw < 2; kw++)
#pragma unroll
                for (int ic = 0; ic < 32; ic++) {
                    float xv = c2[sub][((2 * oh + kh) * 3 + kw) * 32 + ic];
                    ushort4 w = *(const ushort4*)&wl[2608 + ((kh * 2 + kw) * 32 + ic) * 64 + g * 4];
                    a0 += xv * bf(w.x); a1 += xv * bf(w.y);
                    a2 += xv * bf(w.z); a3 += xv * bf(w.w);
                }
        c3[sub][oh * 64 + g * 4]     = lrelu(a0);
        c3[sub][oh * 64 + g * 4 + 1] = lrelu(a1);
        c3[sub][oh * 64 + g * 4 + 2] = lrelu(a2);
        c3[sub][oh * 64 + g * 4 + 3] = lrelu(a3);
    }
    __syncthreads();

    for (int idx = stid; idx < 64; idx += 128) {
        int oh = idx >> 5, g = idx & 31;
        float a0 = bf(wl[19056 + g * 4]), a1 = bf(wl[19057 + g * 4]),
              a2 = bf(wl[19058 + g * 4]), a3 = bf(wl[19059 + g * 4]);
#pragma unroll
        for (int ic = 0; ic < 64; ic++) {
            float xv = c3[sub][oh * 64 + ic];
            ushort4 w = *(const ushort4*)&wl[10864 + ic * 128 + g * 4];
            a0 += xv * bf(w.x); a1 += xv * bf(w.y);
            a2 += xv * bf(w.z); a3 += xv * bf(w.w);
        }
        P.featbf[bt * 256 + (g * 4 + 0) * 2 + oh] = f2b(lrelu(a0));
        P.featbf[bt * 256 + (g * 4 + 1) * 2 + oh] = f2b(lrelu(a1));
        P.featbf[bt * 256 + (g * 4 + 2) * 2 + oh] = f2b(lrelu(a2));
        P.featbf[bt * 256 + (g * 4 + 3) * 2 + oh] = f2b(lrelu(a3));
    }
}

// ================= K2: zx = featbf @ Wk + b (MFMA) ==========================
__global__ __launch_bounds__(256) void gemm_zx(
    const u16* __restrict__ Abf, const u16* __restrict__ PB,
    const void* __restrict__ bias, const int* __restrict__ flag,
    float* __restrict__ out)
{
    __shared__ __align__(16) u16 As[16 * 264];
    const int mb = blockIdx.y, nb = blockIdx.x, tid = threadIdx.x;
    const int f32 = *flag;
    const int m0 = mb * 16;
    {
        int row = tid >> 4, part = tid & 15;
        const f32x4* src = (const f32x4*)&Abf[(size_t)(m0 + row) * 256 + part * 16];
        f32x4 v0 = src[0], v1 = src[1];
        *(f32x4*)&As[row * 264 + part * 16] = v0;
        *(f32x4*)&As[row * 264 + part * 16 + 8] = v1;
    }
    __syncthreads();
    const int wv = tid >> 6, lane = tid & 63;
    const int colw = lane & 15, q = lane >> 4;
    const int n = nb * 64 + wv * 16 + colw;
    f32x4 acc = {0.f, 0.f, 0.f, 0.f};
#pragma unroll
    for (int kt = 0; kt < 8; kt++) {
        short8 a = *(const short8*)&As[colw * 264 + kt * 32 + q * 8];
        short8 b = *(const short8*)&PB[((((size_t)kt << 10) + n) * 4 + q) * 8];
        acc = __builtin_amdgcn_mfma_f32_16x16x32_bf16(a, b, acc, 0, 0, 0);
    }
    const float bj = ldf(bias, n, f32);
#pragma unroll
    for (int r = 0; r < 4; r++) {
        int row = q * 4 + r;
        out[(size_t)(m0 + row) * 1024 + n] = acc[r] + bj;
    }
}

// ================= K3: LSTM — full Wr CU-resident (384KB VGPR + 128KB LDS) ==
// 64 blocks (1/seq) x 512 threads (8 waves, 2 waves/SIMD -> 256-VGPR cap).
// Thread (c = tid&255, kh = tid>>8) computes K in [128kh, 128kh+128) for the
// 4 gate columns {g*256+c}: 12 octets' weights in VGPRs (48 int4 = 192 regs,
// 64 below the arch cap -> spill-safe) + 4 octets in LDS (128 KB). Zero
// per-step global weight traffic. Per step: 16 uniform h-octet broadcasts
// (half of round-0's 32), 16 weight ds_read_b128, one b128 zp write; gate
// phase is parallel on threads<256 (2x b128 zp read + ~30 VALU), 2 barriers.
#define NREG 12
#define NLDS4 4
__global__ __launch_bounds__(512)
__attribute__((amdgpu_waves_per_eu(2, 2)))
void lstm_kernel(
    const float* __restrict__ zx, const u16* __restrict__ PF,
    u16* __restrict__ hseqbf)
{
    __shared__ __align__(16) u16 h16[264];                     // h(t), f16
    __shared__ __align__(16) float zp[2048];                   // [kh][c][g]
    __shared__ __align__(16) int4 wlds[2][NLDS4][4][256];      // 128 KB
    const int b = blockIdx.x, tid = threadIdx.x;
    const int c = tid & 255, kh = tid >> 8;
    const int4* Pw = (const int4*)PF;

    // weight residency: octets kh*16+0..11 in regs, +12..15 in LDS
    int4 wr[NREG][4];
#pragma unroll
    for (int o = 0; o < NREG; o++)
#pragma unroll
        for (int g = 0; g < 4; g++)
            wr[o][g] = Pw[(size_t)(kh * 16 + o) * 1024 + g * 256 + c];
#pragma unroll
    for (int o = 0; o < NLDS4; o++)
#pragma unroll
        for (int g = 0; g < 4; g++)
            wlds[kh][o][g][c] = Pw[(size_t)(kh * 16 + NREG + o) * 1024 + g * 256 + c];

    if (tid < 132) ((u32*)h16)[tid] = 0u;
    float cst = 0.f;
    const size_t z0 = (size_t)b * TSEQ * 1024;
    float zxv0 = 0.f, zxv1 = 0.f, zxv2 = 0.f, zxv3 = 0.f;
    if (tid < 256) {
        zxv0 = zx[z0 + c];       zxv1 = zx[z0 + 256 + c];
        zxv2 = zx[z0 + 512 + c]; zxv3 = zx[z0 + 768 + c];
    }
    __syncthreads();

    for (int t = 0; t < TSEQ; t++) {
        float a0 = 0.f, a1 = 0.f, a2 = 0.f, a3 = 0.f;
#pragma unroll
        for (int o = 0; o < NREG; o++) {
            int4 hv = *(const int4*)&h16[(kh * 16 + o) * 8];
            a0 = dot2(hv.x, wr[o][0].x, a0); a0 = dot2(hv.y, wr[o][0].y, a0);
            a0 = dot2(hv.z, wr[o][0].z, a0); a0 = dot2(hv.w, wr[o][0].w, a0);
            a1 = dot2(hv.x, wr[o][1].x, a1); a1 = dot2(hv.y, wr[o][1].y, a1);
            a1 = dot2(hv.z, wr[o][1].z, a1); a1 = dot2(hv.w, wr[o][1].w, a1);
            a2 = dot2(hv.x, wr[o][2].x, a2); a2 = dot2(hv.y, wr[o][2].y, a2);
            a2 = dot2(hv.z, wr[o][2].z, a2); a2 = dot2(hv.w, wr[o][2].w, a2);
            a3 = dot2(hv.x, wr[o][3].x, a3); a3 = dot2(hv.y, wr[o][3].y, a3);
            a3 = dot2(hv.z, wr[o][3].z, a3); a3 = dot2(hv.w, wr[o][3].w, a3);
        }
#pragma unroll
        for (int o = 0; o < NLDS4; o++) {
            int4 hv = *(const int4*)&h16[(kh * 16 + NREG + o) * 8];
            int4 w0 = wlds[kh][o][0][c];
            int4 w1 = wlds[kh][o][1][c];
            int4 w2 = wlds[kh][o][2][c];
            int4 w3 = wlds[kh][o][3][c];
            a0 = dot2(hv.x, w0.x, a0); a0 = dot2(hv.y, w0.y, a0);
            a0 = dot2(hv.z, w0.z, a0); a0 = dot2(hv.w, w0.w, a0);
            a1 = dot2(hv.x, w1.x, a1); a1 = dot2(hv.y, w1.y, a1);
            a1 = dot2(hv.z, w1.z, a1); a1 = dot2(hv.w, w1.w, a1);
            a2 = dot2(hv.x, w2.x, a2); a2 = dot2(hv.y, w2.y, a2);
            a2 = dot2(hv.z, w2.z, a2); a2 = dot2(hv.w, w2.w, a2);
            a3 = dot2(hv.x, w3.x, a3); a3 = dot2(hv.y, w3.y, a3);
            a3 = dot2(hv.z, w3.z, a3); a3 = dot2(hv.w, w3.w, a3);
        }
        *(f32x4*)&zp[((kh << 8) + c) * 4] = (f32x4){a0, a1, a2, a3};
        __syncthreads();

        if (tid < 256) {
            f32x4 s0 = *(const f32x4*)&zp[c * 4];
            f32x4 s1 = *(const f32x4*)&zp[1024 + c * 4];
            float zi = s0.x + s1.x + zxv0;
            float zf = s0.y + s1.y + zxv1;
            float zg = s0.z + s1.z + zxv2;
            float zo = s0.w + s1.w + zxv3;
            // prefetch next-step zx (consumed ~1 full step later)
            if (t + 1 < TSEQ) {
                const size_t zr = z0 + (size_t)(t + 1) * 1024;
                zxv0 = zx[zr + c];       zxv1 = zx[zr + 256 + c];
                zxv2 = zx[zr + 512 + c]; zxv3 = zx[zr + 768 + c];
            }
            float ig = fsigm(zi), fg = fsigm(zf), og = fsigm(zo);
            float gg = ftanh(zg);
            cst = fg * cst + ig * gg;
            float h = og * ftanh(cst);
            h16[c] = __builtin_bit_cast(unsigned short, (_Float16)h);
            hseqbf[(size_t)b * (TSEQ * 256) + t * 256 + c] = f2b(h);
        }
        __syncthreads();
    }
}

// ================= K4: pir head + vpred (64 blocks) =========================
__global__ __launch_bounds__(256) void pir_kernel(
    const u16* __restrict__ Abf, const u16* __restrict__ PB,
    const void* __restrict__ pir_b, const void* __restrict__ v_b,
    const int* __restrict__ flag, const int* __restrict__ a_taken,
    float* __restrict__ entpir, float* __restrict__ ppira, float* __restrict__ vpred)
{
    __shared__ __align__(16) u16 As[64 * 264];
    const int tid = threadIdx.x;
    const int wv = tid >> 6, lane = tid & 63;
    const int colw = lane & 15, q = lane >> 4;
    const int f32 = *flag;
    const int m0 = blockIdx.x * 64;

    for (int idx = tid; idx < 1024; idx += 256) {
        int row = idx >> 4, part = idx & 15;
        const f32x4* src = (const f32x4*)&Abf[(size_t)(m0 + row) * 256 + part * 16];
        f32x4 v0 = src[0], v1 = src[1];
        *(f32x4*)&As[row * 264 + part * 16] = v0;
        *(f32x4*)&As[row * 264 + part * 16 + 8] = v1;
    }
    __syncthreads();
    f32x4 acc[4];
#pragma unroll
    for (int nt = 0; nt < 4; nt++) acc[nt] = (f32x4){0.f, 0.f, 0.f, 0.f};
#pragma unroll
    for (int kt = 0; kt < 8; kt++) {
        short8 a = *(const short8*)&As[(wv * 16 + colw) * 264 + kt * 32 + q * 8];
#pragma unroll
        for (int nt = 0; nt < 4; nt++) {
            short8 b = *(const short8*)&PB[((((size_t)kt * 64) + nt * 16 + colw) * 4 + q) * 8];
            acc[nt] = __builtin_amdgcn_mfma_f32_16x16x32_bf16(a, b, acc[nt], 0, 0, 0);
        }
    }
    float* zq = (float*)&As[wv * 4224];   // wave-local 16x65 overlay
#pragma unroll
    for (int nt = 0; nt < 4; nt++) {
        int col = nt * 16 + colw;
        float bj = (col < 36) ? ldf(pir_b, col, f32)
                              : (col == 36 ? ldf(v_b, 0, f32) : 0.f);
#pragma unroll
        for (int r = 0; r < 4; r++)
            zq[(q * 4 + r) * 65 + col] = acc[nt][r] + bj;
    }
    if (lane < 16) {
        int R = m0 + wv * 16 + lane;
        const float* zrow = &zq[lane * 65];
        float Z = 0.f, U = 0.f;
        for (int cc = 0; cc < 36; cc++) {
            float z = zrow[cc];
            float ev = __expf(z);
            Z += ev; U += ev * z;
        }
        entpir[R] = logf(Z) - U / Z;
        ppira[R]  = __expf(zrow[a_taken[R]]) / Z;
        vpred[R]  = zrow[36];
    }
}

// ================= K5: pim — M=32 tiles, fused masked-softmax partials ======
__global__ __launch_bounds__(256) void pim_kernel(
    const u16* __restrict__ Abf, const u16* __restrict__ PB,
    const void* __restrict__ pim_b, const int* __restrict__ flag,
    const int* __restrict__ mask, const int* __restrict__ a_taken,
    float* __restrict__ partS, float* __restrict__ partU, float* __restrict__ za)
{
    __shared__ __align__(16) u16 As[32 * 264];   // 16.9 KB
    __shared__ float redS[4][32], redU[4][32];
    const int nb = blockIdx.x, mb = blockIdx.y, tid = threadIdx.x;
    const int wv = tid >> 6, lane = tid & 63;
    const int colw = lane & 15, q = lane >> 4;
    const int f32 = *flag;
    const int m0 = mb * 32;

    for (int idx = tid; idx < 512; idx += 256) {
        int row = idx >> 4, part = idx & 15;
        const f32x4* src = (const f32x4*)&Abf[(size_t)(m0 + row) * 256 + part * 16];
        f32x4 v0 = src[0], v1 = src[1];
        *(f32x4*)&As[row * 264 + part * 16] = v0;
        *(f32x4*)&As[row * 264 + part * 16 + 8] = v1;
    }
    __syncthreads();
    const int n = nb * 64 + wv * 16 + colw;
    f32x4 acc0 = {0.f, 0.f, 0.f, 0.f}, acc1 = {0.f, 0.f, 0.f, 0.f};
#pragma unroll
    for (int kt = 0; kt < 8; kt++) {
        short8 b = *(const short8*)&PB[((((size_t)kt << 12) + n) * 4 + q) * 8];
        short8 a0 = *(const short8*)&As[colw * 264 + kt * 32 + q * 8];
        short8 a1 = *(const short8*)&As[(16 + colw) * 264 + kt * 32 + q * 8];
        acc0 = __builtin_amdgcn_mfma_f32_16x16x32_bf16(a0, b, acc0, 0, 0, 0);
        acc1 = __builtin_amdgcn_mfma_f32_16x16x32_bf16(a1, b, acc1, 0, 0, 0);
    }
    const float bj = ldf(pim_b, n, f32);
#pragma unroll
    for (int half = 0; half < 2; half++) {
        const f32x4& acc = half ? acc1 : acc0;
        float sv[4], uv[4];
#pragma unroll
        for (int r = 0; r < 4; r++) {
            int row = m0 + half * 16 + q * 4 + r;
            float z = acc[r] + bj;
            int mm = mask[(size_t)row * 4096 + n];
            float ev = __expf(z);
            sv[r] = mm ? ev : 0.f;
            uv[r] = mm ? ev * z : 0.f;
            if (n == a_taken[row]) za[row] = z;
        }
#pragma unroll
        for (int r = 0; r < 4; r++) {
            for (int off = 1; off < 16; off <<= 1) {
                sv[r] += __shfl_xor(sv[r], off, 16);
                uv[r] += __shfl_xor(uv[r], off, 16);
            }
            if (colw == 0) {
                redS[wv][half * 16 + q * 4 + r] = sv[r];
                redU[wv][half * 16 + q * 4 + r] = uv[r];
            }
        }
    }
    __syncthreads();
    if (tid < 32) {
        float S = redS[0][tid] + redS[1][tid] + redS[2][tid] + redS[3][tid];
        float U = redU[0][tid] + redU[1][tid] + redU[2][tid] + redU[3][tid];
        partS[(size_t)(m0 + tid) * 64 + nb] = S;
        partU[(size_t)(m0 + tid) * 64 + nb] = U;
    }
}

// ================= K6: tail = pimfin + gae + pg + vf + fin (ticket) =========
#define TAIL_BLOCKS (16 + 256)
__global__ __launch_bounds__(256) void tail_kernel(
    const float* __restrict__ partS, const float* __restrict__ partU,
    const float* __restrict__ za,
    const float* __restrict__ entpir, const float* __restrict__ ppira,
    const float* __restrict__ vpred,
    const void* __restrict__ lgold, const void* __restrict__ gae,
    const void* __restrict__ ovp, const void* __restrict__ ret,
    float* __restrict__ scal, const int* __restrict__ flag,
    void* __restrict__ out)
{
    const int bid = blockIdx.x, tid = threadIdx.x;
    const int f32 = *flag;
    __shared__ float sh[8];
    __shared__ float mst[2];
    if (bid < 16) {
        const int r = bid * 256 + tid;
        float S = 0.f, U = 0.f;
#pragma unroll
        for (int t2 = 0; t2 < 64; t2++) {
            S += partS[(size_t)r * 64 + t2];
            U += partU[(size_t)r * 64 + t2];
        }
        float entpim = logf(S) - U / S;
        float ppima = __expf(za[r]) / S;
        float s = 0.f, s2 = 0.f;
        if (f32) {
            const float* gp = (const float*)gae;
            for (int i = tid; i < BT; i += 256) { float v = gp[i]; s += v; s2 += v * v; }
        } else {
            const u16* gp = (const u16*)gae;
            for (int i = tid; i < BT; i += 256) { float v = bf(gp[i]); s += v; s2 += v * v; }
        }
        for (int off = 32; off; off >>= 1) {
            s += __shfl_down(s, off, 64); s2 += __shfl_down(s2, off, 64);
        }
        if ((tid & 63) == 0) { sh[tid >> 6] = s; sh[4 + (tid >> 6)] = s2; }
        __syncthreads();
        if (tid == 0) {
            float Sa = sh[0] + sh[1] + sh[2] + sh[3];
            float S2a = sh[4] + sh[5] + sh[6] + sh[7];
            float mean = Sa / (float)BT;
            float var = S2a / (float)BT - mean * mean;
            mst[0] = mean; mst[1] = sqrtf(fmaxf(var, 0.f));
        }
        __syncthreads();
        float mean = mst[0], sd = mst[1];
        float p = (r & 1) ? ppima : ppira[r];
        float ln = logf(p);
        float rt = __expf(ln - ldf(lgold, r, f32));
        float g = (ldf(gae, r, f32) - mean) / (sd + 1e-8f);
        float rtc = fminf(fmaxf(rt, 0.8f), 1.2f);
        float pg = fmaxf(-g * rt, -g * rtc);
        float e12 = entpir[r] + entpim;
        for (int off = 32; off; off >>= 1) {
            pg += __shfl_down(pg, off, 64);
            e12 += __shfl_down(e12, off, 64);
        }
        if ((tid & 63) == 0) {
            atomicAdd(&scal[2], pg);
            atomicAdd(&scal[3], e12);
        }
    } else {
        const int i0 = (bid - 16) * 16;
        float s = 0.f;
        if (f32) {
            const float* rp = (const float*)ret;
            const float* op = (const float*)ovp;
            for (int rr = 0; rr < 16; rr++) {
                float vp = vpred[i0 + rr];
                for (int j = tid; j < BT; j += 256) {
                    float r2 = rp[j], o = op[j];
                    float d = fminf(fmaxf(vp - o, -0.2f), 0.2f);
                    float v1 = vp - r2;    v1 *= v1;
                    float v2 = o + d - r2; v2 *= v2;
                    s += fmaxf(v1, v2);
                }
            }
        } else {
            const u16* rp = (const u16*)ret;
            const u16* op = (const u16*)ovp;
            for (int rr = 0; rr < 16; rr++) {
                float vp = vpred[i0 + rr];
                for (int j = tid; j < BT; j += 256) {
                    float r2 = bf(rp[j]), o = bf(op[j]);
                    float d = fminf(fmaxf(vp - o, -0.2f), 0.2f);
                    float v1 = vp - r2;    v1 *= v1;
                    float v2 = o + d - r2; v2 *= v2;
                    s += fmaxf(v1, v2);
                }
            }
        }
        for (int off = 32; off; off >>= 1) s += __shfl_down(s, off, 64);
        if ((tid & 63) == 0) sh[tid >> 6] = s;
        __syncthreads();
        if (tid == 0) atomicAdd(&scal[5], sh[0] + sh[1] + sh[2] + sh[3]);
    }
    __threadfence();
    __syncthreads();
    if (tid == 0) {
        unsigned old = atomicAdd((unsigned int*)&scal[8], 1u);
        if (old == TAIL_BLOCKS - 1) {
            __threadfence();
            float pgs = atomicAdd(&scal[2], 0.f);
            float ents = atomicAdd(&scal[3], 0.f);
            float vfs = atomicAdd(&scal[5], 0.f);
            float pg = pgs / (float)BT;
            float vf = 0.5f * vfs / ((float)BT * (float)BT);
            float loss = pg - ents + vf;
            if (f32) {
                float* o = (float*)out;
                o[0] = loss; o[1] = pg; o[2] = ents; o[3] = vf;
            } else {
                u16* o = (u16*)out;
                o[0] = f2b(loss); o[1] = f2b(pg); o[2] = f2b(ents); o[3] = f2b(vf);
            }
        }
    }
}

extern "C" void kernel_launch(void* const* d_in, const int* in_sizes, int n_in,
                              void* d_out, int out_size, void* d_ws, size_t ws_size,
                              hipStream_t stream)
{
    const int* mask = (const int*)d_in[1];
    const int* a_tk = (const int*)d_in[3];

    float* p = (float*)d_ws;
    u16*   featbf = (u16*)p;            p += 524288;    // 1M u16
    float* zx     = p;                  p += 4194304;   // 16 MB
    u16*   hseqbf = (u16*)p;            p += 524288;    // 1M u16
    u16*   PF     = (u16*)p;            p += 131072;    // f16 Wr
    u16*   PBk    = (u16*)p;            p += 131072;    // bf16 Wk frag
    u16*   PBpim  = (u16*)p;            p += 524288;    // bf16 pimW frag
    u16*   PBpir  = (u16*)p;            p += 8192;      // bf16 [pirW|vW] frag
    float* scal   = p;                  p += 32;
    int*   flag   = (int*)p;            p += 4;
    float* partS  = p;                  p += 262144;
    float* partU  = p;                  p += 262144;
    float* za     = p;                  p += 4096;
    float* entpir = p;                  p += 4096;
    float* ppira  = p;                  p += 4096;
    float* vpred  = p;                  p += 4096;

    PrepPtrs P;
    P.x = d_in[0];
    P.W1 = d_in[7];  P.b1 = d_in[8];
    P.W2 = d_in[9];  P.b2 = d_in[10];
    P.W3 = d_in[11]; P.b3 = d_in[12];
    P.W4 = d_in[13]; P.b4 = d_in[14];
    P.Wk = d_in[15]; P.Wr = d_in[16];
    P.Wpir = d_in[18]; P.Wpim = d_in[20]; P.Wv = d_in[22];
    P.probe = (const u16*)d_in[15];
    P.featbf = featbf; P.PF = PF; P.PBk = PBk; P.PBpim = PBpim; P.PBpir = PBpir;
    P.scal = scal; P.flag = flag;

    prep_kernel<<<PACK_BLKS + CONV_BLKS, 256, 0, stream>>>(P);
    gemm_zx<<<dim3(16, 256), 256, 0, stream>>>(featbf, PBk, d_in[17], flag, zx);
    lstm_kernel<<<NB, 512, 0, stream>>>(zx, PF, hseqbf);
    pir_kernel<<<64, 256, 0, stream>>>(hseqbf, PBpir, d_in[19], d_in[23], flag,
                                       a_tk, entpir, ppira, vpred);
    pim_kernel<<<dim3(64, 128), 256, 0, stream>>>(hseqbf, PBpim, d_in[21], flag,
                                                  mask, a_tk, partS, partU, za);
    tail_kernel<<<TAIL_BLOCKS, 256, 0, stream>>>(
        partS, partU, za, entpir, ppira, vpred,
        d_in[2], d_in[4], d_in[5], d_in[6], scal, flag, (void*)d_out);
}

// Round 4
// 450.463 us; speedup vs baseline: 2.3301x; 1.0095x over previous
//
#include <hip/hip_runtime.h>

typedef unsigned short u16;
typedef unsigned int   u32;

#define BT   4096
#define TSEQ 64
#define NB   64

typedef __attribute__((ext_vector_type(8))) short  short8;
typedef __attribute__((ext_vector_type(4))) float  f32x4;
typedef __attribute__((ext_vector_type(4))) int    i32x4;
typedef __attribute__((ext_vector_type(2))) _Float16 h2;

__device__ __forceinline__ float bf(u16 v) {
    u32 u = ((u32)v) << 16;
    return __builtin_bit_cast(float, u);
}
__device__ __forceinline__ u16 f2b(float f) {
    u32 u = __builtin_bit_cast(u32, f);
    return (u16)((u + 0x7fffu + ((u >> 16) & 1u)) >> 16);  // RNE
}
__device__ __forceinline__ float lrelu(float x) { return x > 0.f ? x : 0.2f * x; }
__device__ __forceinline__ h2 i2h(int v) { return __builtin_bit_cast(h2, v); }
__device__ __forceinline__ float dot2(int hbits, int wbits, float acc) {
#if __has_builtin(__builtin_amdgcn_fdot2)
    return __builtin_amdgcn_fdot2(i2h(hbits), i2h(wbits), acc, false);
#else
    h2 a = i2h(hbits), b = i2h(wbits);
    return acc + (float)a.x * (float)b.x + (float)a.y * (float)b.y;
#endif
}
__device__ __forceinline__ float fsigm(float x) { return 1.f / (1.f + __expf(-x)); }
__device__ __forceinline__ float ftanh(float x) { return 1.f - 2.f / (__expf(2.f * x) + 1.f); }
__device__ __forceinline__ float ldf(const void* p, int i, int f32) {
    return f32 ? ((const float*)p)[i] : bf(((const u16*)p)[i]);
}
__device__ __forceinline__ u16 ldb(const void* p, int i, int f32) {
    return f32 ? f2b(((const float*)p)[i]) : ((const u16*)p)[i];
}

struct PrepPtrs {
    const void *x, *W1, *b1, *W2, *b2, *W3, *b3, *W4, *b4;
    const void *Wr, *Wk, *Wpim, *Wpir, *Wv;
    const u16* probe;
    u16 *featbf, *PF, *PBk, *PBpim, *PBpir;
    float* scal; int* flag;
};

// pack: each thread packs 8 consecutive k (one octet) for one column ->
// 8 coalesced reads + one contiguous 16B store (old: 2B scatter, ~16x WA)
#define PACK_BLKS 776   // PF 128 | PBk 128 | PBpim 512 | PBpir 8
#define CONV_BLKS 2048  // 2 images per block

// ================= K1: prep = sniff(inline) + pack + conv ===================
__global__ __launch_bounds__(256) void prep_kernel(PrepPtrs P)
{
    const int bid = blockIdx.x, tid = threadIdx.x;
    const int lane = tid & 63;
    u16 pv = P.probe[2 * lane];
    int e = (pv >> 7) & 0xFF;
    unsigned long long m = __ballot(pv == 0 || (e >= 100 && e <= 130));
    const int f32 = (__popcll(m) < 48) ? 1 : 0;

    if (bid == 0 && tid < 32) { P.scal[tid] = 0.f; if (tid == 0) *P.flag = f32; }

    if (bid < PACK_BLKS) {
        u16 t8[8];
        if (bid < 128) {                       // PF: Wr -> f16 chunks
            int gid = bid * 256 + tid;         // 32768: (oct, col)
            int col = gid & 1023, oct = gid >> 10;
#pragma unroll
            for (int j = 0; j < 8; j++) {
                float f = ldf(P.Wr, (oct * 8 + j) * 1024 + col, f32);
                _Float16 h = (_Float16)f;
                t8[j] = __builtin_bit_cast(unsigned short, h);
            }
            *(int4*)&P.PF[((size_t)oct * 1024 + col) * 8] = *(int4*)t8;
        } else if (bid < 256) {                // PBk: bf16 B-frag
            int gid = (bid - 128) * 256 + tid;
            int col = gid & 1023, oct = gid >> 10;
#pragma unroll
            for (int j = 0; j < 8; j++) t8[j] = ldb(P.Wk, (oct * 8 + j) * 1024 + col, f32);
            *(int4*)&P.PBk[((((size_t)(oct >> 2) << 10) + col) * 4 + (oct & 3)) * 8] = *(int4*)t8;
        } else if (bid < 768) {                // PBpim
            int gid = (bid - 256) * 256 + tid; // 131072: (oct, col)
            int col = gid & 4095, oct = gid >> 12;
#pragma unroll
            for (int j = 0; j < 8; j++) t8[j] = ldb(P.Wpim, (size_t)(oct * 8 + j) * 4096 + col, f32);
            *(int4*)&P.PBpim[((((size_t)(oct >> 2) << 12) + col) * 4 + (oct & 3)) * 8] = *(int4*)t8;
        } else {                               // PBpir: [pirW|vW|0]
            int gid = (bid - 768) * 256 + tid; // 2048: (oct, col)
            int col = gid & 63, oct = gid >> 6;
#pragma unroll
            for (int j = 0; j < 8; j++) {
                int k = oct * 8 + j;
                u16 v = 0;
                if (col < 36)       v = ldb(P.Wpir, k * 36 + col, f32);
                else if (col == 36) v = ldb(P.Wv, k, f32);
                t8[j] = v;
            }
            *(int4*)&P.PBpir[(((size_t)(oct >> 2) * 64 + col) * 4 + (oct & 3)) * 8] = *(int4*)t8;
        }
        return;
    }

    // ---- conv branch: 2 images per block; LDS-staged bf16 weights ----
    __shared__ __align__(16) u16 wl[19184];
    __shared__ float xs[2][832];
    __shared__ float c1[2][384];
    __shared__ float c2[2][480];
    __shared__ float c3[2][128];
    const int pair = bid - PACK_BLKS;
    const int sub = tid >> 7, stid = tid & 127;
    const int bt = pair * 2 + sub;

    {
        const void* sp[8] = {P.W1, P.b1, P.W2, P.b2, P.W3, P.b3, P.W4, P.b4};
        const int   sn[8] = {512, 16, 2048, 32, 8192, 64, 8192, 128};
        int o = 0;
        for (int s = 0; s < 8; s++) {
            for (int i = tid; i < sn[s]; i += 256) wl[o + i] = ldb(sp[s], i, f32);
            o += sn[s];
        }
    }
    for (int i = stid; i < 832; i += 128) xs[sub][i] = ldf(P.x, bt * 832 + i, f32);
    __syncthreads();

    for (int idx = stid; idx < 96; idx += 128) {
        int pos = idx >> 2, g = idx & 3;
        int oh = pos >> 2, ow = pos & 3;
        float a0 = bf(wl[512 + g * 4]), a1 = bf(wl[513 + g * 4]),
              a2 = bf(wl[514 + g * 4]), a3 = bf(wl[515 + g * 4]);
        for (int kh = 0; kh < 2; kh++)
            for (int kw = 0; kw < 2; kw++)
#pragma unroll
                for (int ic = 0; ic < 8; ic++) {
                    float xv = xs[sub][(2 * oh + kh) * 64 + (2 * ow + kw) * 8 + ic];
                    ushort4 w = *(const ushort4*)&wl[((kh * 2 + kw) * 8 + ic) * 16 + g * 4];
                    a0 += xv * bf(w.x); a1 += xv * bf(w.y);
                    a2 += xv * bf(w.z); a3 += xv * bf(w.w);
                }
        c1[sub][pos * 16 + g * 4]     = lrelu(a0);
        c1[sub][pos * 16 + g * 4 + 1] = lrelu(a1);
        c1[sub][pos * 16 + g * 4 + 2] = lrelu(a2);
        c1[sub][pos * 16 + g * 4 + 3] = lrelu(a3);
    }
    __syncthreads();

    for (int idx = stid; idx < 120; idx += 128) {
        int pos = idx >> 3, g = idx & 7;
        int oh = pos / 3, ow = pos % 3;
        float a0 = bf(wl[2576 + g * 4]), a1 = bf(wl[2577 + g * 4]),
              a2 = bf(wl[2578 + g * 4]), a3 = bf(wl[2579 + g * 4]);
        for (int kh = 0; kh < 2; kh++)
            for (int kw = 0; kw < 2; kw++)
#pragma unroll
                for (int ic = 0; ic < 16; ic++) {
                    float xv = c1[sub][((oh + kh) * 4 + (ow + kw)) * 16 + ic];
                    ushort4 w = *(const ushort4*)&wl[528 + ((kh * 2 + kw) * 16 + ic) * 32 + g * 4];
                    a0 += xv * bf(w.x); a1 += xv * bf(w.y);
                    a2 += xv * bf(w.z); a3 += xv * bf(w.w);
                }
        c2[sub][pos * 32 + g * 4]     = lrelu(a0);
        c2[sub][pos * 32 + g * 4 + 1] = lrelu(a1);
        c2[sub][pos * 32 + g * 4 + 2] = lrelu(a2);
        c2[sub][pos * 32 + g * 4 + 3] = lrelu(a3);
    }
    __syncthreads();

    for (int idx = stid; idx < 32; idx += 128) {
        int oh = idx >> 4, g = idx & 15;
        float a0 = bf(wl[10800 + g * 4]), a1 = bf(wl[10801 + g * 4]),
              a2 = bf(wl[10802 + g * 4]), a3 = bf(wl[10803 + g * 4]);
        for (int kh = 0; kh < 2; kh++)
            for (int kw = 0; kw < 2; kw++)
#pragma unroll
                for (int ic = 0; ic < 32; ic++) {
                    float xv = c2[sub][((2 * oh + kh) * 3 + kw) * 32 + ic];
                    ushort4 w = *(const ushort4*)&wl[2608 + ((kh * 2 + kw) * 32 + ic) * 64 + g * 4];
                    a0 += xv * bf(w.x); a1 += xv * bf(w.y);
                    a2 += xv * bf(w.z); a3 += xv * bf(w.w);
                }
        c3[sub][oh * 64 + g * 4]     = lrelu(a0);
        c3[sub][oh * 64 + g * 4 + 1] = lrelu(a1);
        c3[sub][oh * 64 + g * 4 + 2] = lrelu(a2);
        c3[sub][oh * 64 + g * 4 + 3] = lrelu(a3);
    }
    __syncthreads();

    for (int idx = stid; idx < 64; idx += 128) {
        int oh = idx >> 5, g = idx & 31;
        float a0 = bf(wl[19056 + g * 4]), a1 = bf(wl[19057 + g * 4]),
              a2 = bf(wl[19058 + g * 4]), a3 = bf(wl[19059 + g * 4]);
#pragma unroll
        for (int ic = 0; ic < 64; ic++) {
            float xv = c3[sub][oh * 64 + ic];
            ushort4 w = *(const ushort4*)&wl[10864 + ic * 128 + g * 4];
            a0 += xv * bf(w.x); a1 += xv * bf(w.y);
            a2 += xv * bf(w.z); a3 += xv * bf(w.w);
        }
        P.featbf[bt * 256 + (g * 4 + 0) * 2 + oh] = f2b(lrelu(a0));
        P.featbf[bt * 256 + (g * 4 + 1) * 2 + oh] = f2b(lrelu(a1));
        P.featbf[bt * 256 + (g * 4 + 2) * 2 + oh] = f2b(lrelu(a2));
        P.featbf[bt * 256 + (g * 4 + 3) * 2 + oh] = f2b(lrelu(a3));
    }
}

// ================= K2: zx = featbf @ Wk + b (MFMA) ==========================
__global__ __launch_bounds__(256) void gemm_zx(
    const u16* __restrict__ Abf, const u16* __restrict__ PB,
    const void* __restrict__ bias, const int* __restrict__ flag,
    float* __restrict__ out)
{
    __shared__ __align__(16) u16 As[16 * 264];
    const int mb = blockIdx.y, nb = blockIdx.x, tid = threadIdx.x;
    const int f32 = *flag;
    const int m0 = mb * 16;
    {
        int row = tid >> 4, part = tid & 15;
        const f32x4* src = (const f32x4*)&Abf[(size_t)(m0 + row) * 256 + part * 16];
        f32x4 v0 = src[0], v1 = src[1];
        *(f32x4*)&As[row * 264 + part * 16] = v0;
        *(f32x4*)&As[row * 264 + part * 16 + 8] = v1;
    }
    __syncthreads();
    const int wv = tid >> 6, lane = tid & 63;
    const int colw = lane & 15, q = lane >> 4;
    const int n = nb * 64 + wv * 16 + colw;
    f32x4 acc = {0.f, 0.f, 0.f, 0.f};
#pragma unroll
    for (int kt = 0; kt < 8; kt++) {
        short8 a = *(const short8*)&As[colw * 264 + kt * 32 + q * 8];
        short8 b = *(const short8*)&PB[((((size_t)kt << 10) + n) * 4 + q) * 8];
        acc = __builtin_amdgcn_mfma_f32_16x16x32_bf16(a, b, acc, 0, 0, 0);
    }
    const float bj = ldf(bias, n, f32);
#pragma unroll
    for (int r = 0; r < 4; r++) {
        int row = q * 4 + r;
        out[(size_t)(m0 + row) * 1024 + n] = acc[r] + bj;
    }
}

// ================= K3: LSTM — full Wr CU-resident, asm-pinned VGPRs =========
// 64 blocks (1/seq) x 512 threads (8 waves, 2 waves/SIMD -> 256-VGPR cap).
// Thread (c = tid&255, kh = tid>>8) computes K in [128kh, 128kh+128) for the
// 4 gate columns {g*256+c}: 12 octets in VGPRs (48 int4 = 192 regs) + 4
// octets in LDS (128 KB). ROUND-3 LESSON: LLVM rematerializes loads from
// __restrict const memory instead of keeping them in registers (VGPR=128,
// weights re-streamed from L2 every step -> 4020 cy/step). The opaque
// `asm volatile("" : "+v")` pin below makes remat illegal, forcing true
// register residency. Tripwire: WRITE_SIZE jump = scratch spill = fail.
#define NREG 12
#define NLDS4 4
__global__ __launch_bounds__(512)
__attribute__((amdgpu_waves_per_eu(2, 2)))
void lstm_kernel(
    const float* __restrict__ zx, const u16* __restrict__ PF,
    u16* __restrict__ hseqbf)
{
    __shared__ __align__(16) u16 h16[264];                     // h(t), f16
    __shared__ __align__(16) float zp[2048];                   // [kh][c][g]
    __shared__ __align__(16) int4 wlds[2][NLDS4][4][256];      // 128 KB
    const int b = blockIdx.x, tid = threadIdx.x;
    const int c = tid & 255, kh = tid >> 8;
    const int4* Pw = (const int4*)PF;

    // weight residency: octets kh*16+0..11 in regs (pinned), +12..15 in LDS
    i32x4 wr[NREG][4];
#pragma unroll
    for (int o = 0; o < NREG; o++)
#pragma unroll
        for (int g = 0; g < 4; g++) {
            int4 v = Pw[(size_t)(kh * 16 + o) * 1024 + g * 256 + c];
            wr[o][g] = (i32x4){v.x, v.y, v.z, v.w};
        }
#pragma unroll
    for (int o = 0; o < NREG; o++)
#pragma unroll
        for (int g = 0; g < 4; g++)
            asm volatile("" : "+v"(wr[o][g]));   // opaque: forbid remat
#pragma unroll
    for (int o = 0; o < NLDS4; o++)
#pragma unroll
        for (int g = 0; g < 4; g++)
            wlds[kh][o][g][c] = Pw[(size_t)(kh * 16 + NREG + o) * 1024 + g * 256 + c];

    if (tid < 132) ((u32*)h16)[tid] = 0u;
    float cst = 0.f;
    const size_t z0 = (size_t)b * TSEQ * 1024;
    float zxv0 = 0.f, zxv1 = 0.f, zxv2 = 0.f, zxv3 = 0.f;
    if (tid < 256) {
        zxv0 = zx[z0 + c];       zxv1 = zx[z0 + 256 + c];
        zxv2 = zx[z0 + 512 + c]; zxv3 = zx[z0 + 768 + c];
    }
    __syncthreads();

    for (int t = 0; t < TSEQ; t++) {
        float a0 = 0.f, a1 = 0.f, a2 = 0.f, a3 = 0.f;
#pragma unroll
        for (int o = 0; o < NREG; o++) {
            int4 hv = *(const int4*)&h16[(kh * 16 + o) * 8];
            a0 = dot2(hv.x, wr[o][0].x, a0); a0 = dot2(hv.y, wr[o][0].y, a0);
            a0 = dot2(hv.z, wr[o][0].z, a0); a0 = dot2(hv.w, wr[o][0].w, a0);
            a1 = dot2(hv.x, wr[o][1].x, a1); a1 = dot2(hv.y, wr[o][1].y, a1);
            a1 = dot2(hv.z, wr[o][1].z, a1); a1 = dot2(hv.w, wr[o][1].w, a1);
            a2 = dot2(hv.x, wr[o][2].x, a2); a2 = dot2(hv.y, wr[o][2].y, a2);
            a2 = dot2(hv.z, wr[o][2].z, a2); a2 = dot2(hv.w, wr[o][2].w, a2);
            a3 = dot2(hv.x, wr[o][3].x, a3); a3 = dot2(hv.y, wr[o][3].y, a3);
            a3 = dot2(hv.z, wr[o][3].z, a3); a3 = dot2(hv.w, wr[o][3].w, a3);
        }
#pragma unroll
        for (int o = 0; o < NLDS4; o++) {
            int4 hv = *(const int4*)&h16[(kh * 16 + NREG + o) * 8];
            int4 w0 = wlds[kh][o][0][c];
            int4 w1 = wlds[kh][o][1][c];
            int4 w2 = wlds[kh][o][2][c];
            int4 w3 = wlds[kh][o][3][c];
            a0 = dot2(hv.x, w0.x, a0); a0 = dot2(hv.y, w0.y, a0);
            a0 = dot2(hv.z, w0.z, a0); a0 = dot2(hv.w, w0.w, a0);
            a1 = dot2(hv.x, w1.x, a1); a1 = dot2(hv.y, w1.y, a1);
            a1 = dot2(hv.z, w1.z, a1); a1 = dot2(hv.w, w1.w, a1);
            a2 = dot2(hv.x, w2.x, a2); a2 = dot2(hv.y, w2.y, a2);
            a2 = dot2(hv.z, w2.z, a2); a2 = dot2(hv.w, w2.w, a2);
            a3 = dot2(hv.x, w3.x, a3); a3 = dot2(hv.y, w3.y, a3);
            a3 = dot2(hv.z, w3.z, a3); a3 = dot2(hv.w, w3.w, a3);
        }
        *(f32x4*)&zp[((kh << 8) + c) * 4] = (f32x4){a0, a1, a2, a3};
        __syncthreads();

        if (tid < 256) {
            f32x4 s0 = *(const f32x4*)&zp[c * 4];
            f32x4 s1 = *(const f32x4*)&zp[1024 + c * 4];
            float zi = s0.x + s1.x + zxv0;
            float zf = s0.y + s1.y + zxv1;
            float zg = s0.z + s1.z + zxv2;
            float zo = s0.w + s1.w + zxv3;
            // prefetch next-step zx (consumed ~1 full step later)
            if (t + 1 < TSEQ) {
                const size_t zr = z0 + (size_t)(t + 1) * 1024;
                zxv0 = zx[zr + c];       zxv1 = zx[zr + 256 + c];
                zxv2 = zx[zr + 512 + c]; zxv3 = zx[zr + 768 + c];
            }
            float ig = fsigm(zi), fg = fsigm(zf), og = fsigm(zo);
            float gg = ftanh(zg);
            cst = fg * cst + ig * gg;
            float h = og * ftanh(cst);
            h16[c] = __builtin_bit_cast(unsigned short, (_Float16)h);
            hseqbf[(size_t)b * (TSEQ * 256) + t * 256 + c] = f2b(h);
        }
        __syncthreads();
    }
}

// ================= K4: pir head + vpred (64 blocks) =========================
__global__ __launch_bounds__(256) void pir_kernel(
    const u16* __restrict__ Abf, const u16* __restrict__ PB,
    const void* __restrict__ pir_b, const void* __restrict__ v_b,
    const int* __restrict__ flag, const int* __restrict__ a_taken,
    float* __restrict__ entpir, float* __restrict__ ppira, float* __restrict__ vpred)
{
    __shared__ __align__(16) u16 As[64 * 264];
    const int tid = threadIdx.x;
    const int wv = tid >> 6, lane = tid & 63;
    const int colw = lane & 15, q = lane >> 4;
    const int f32 = *flag;
    const int m0 = blockIdx.x * 64;

    for (int idx = tid; idx < 1024; idx += 256) {
        int row = idx >> 4, part = idx & 15;
        const f32x4* src = (const f32x4*)&Abf[(size_t)(m0 + row) * 256 + part * 16];
        f32x4 v0 = src[0], v1 = src[1];
        *(f32x4*)&As[row * 264 + part * 16] = v0;
        *(f32x4*)&As[row * 264 + part * 16 + 8] = v1;
    }
    __syncthreads();
    f32x4 acc[4];
#pragma unroll
    for (int nt = 0; nt < 4; nt++) acc[nt] = (f32x4){0.f, 0.f, 0.f, 0.f};
#pragma unroll
    for (int kt = 0; kt < 8; kt++) {
        short8 a = *(const short8*)&As[(wv * 16 + colw) * 264 + kt * 32 + q * 8];
#pragma unroll
        for (int nt = 0; nt < 4; nt++) {
            short8 b = *(const short8*)&PB[((((size_t)kt * 64) + nt * 16 + colw) * 4 + q) * 8];
            acc[nt] = __builtin_amdgcn_mfma_f32_16x16x32_bf16(a, b, acc[nt], 0, 0, 0);
        }
    }
    float* zq = (float*)&As[wv * 4224];   // wave-local 16x65 overlay
#pragma unroll
    for (int nt = 0; nt < 4; nt++) {
        int col = nt * 16 + colw;
        float bj = (col < 36) ? ldf(pir_b, col, f32)
                              : (col == 36 ? ldf(v_b, 0, f32) : 0.f);
#pragma unroll
        for (int r = 0; r < 4; r++)
            zq[(q * 4 + r) * 65 + col] = acc[nt][r] + bj;
    }
    if (lane < 16) {
        int R = m0 + wv * 16 + lane;
        const float* zrow = &zq[lane * 65];
        float Z = 0.f, U = 0.f;
        for (int cc = 0; cc < 36; cc++) {
            float z = zrow[cc];
            float ev = __expf(z);
            Z += ev; U += ev * z;
        }
        entpir[R] = logf(Z) - U / Z;
        ppira[R]  = __expf(zrow[a_taken[R]]) / Z;
        vpred[R]  = zrow[36];
    }
}

// ================= K5: pim — M=32 tiles, fused masked-softmax partials ======
__global__ __launch_bounds__(256) void pim_kernel(
    const u16* __restrict__ Abf, const u16* __restrict__ PB,
    const void* __restrict__ pim_b, const int* __restrict__ flag,
    const int* __restrict__ mask, const int* __restrict__ a_taken,
    float* __restrict__ partS, float* __restrict__ partU, float* __restrict__ za)
{
    __shared__ __align__(16) u16 As[32 * 264];   // 16.9 KB
    __shared__ float redS[4][32], redU[4][32];
    const int nb = blockIdx.x, mb = blockIdx.y, tid = threadIdx.x;
    const int wv = tid >> 6, lane = tid & 63;
    const int colw = lane & 15, q = lane >> 4;
    const int f32 = *flag;
    const int m0 = mb * 32;

    for (int idx = tid; idx < 512; idx += 256) {
        int row = idx >> 4, part = idx & 15;
        const f32x4* src = (const f32x4*)&Abf[(size_t)(m0 + row) * 256 + part * 16];
        f32x4 v0 = src[0], v1 = src[1];
        *(f32x4*)&As[row * 264 + part * 16] = v0;
        *(f32x4*)&As[row * 264 + part * 16 + 8] = v1;
    }
    __syncthreads();
    const int n = nb * 64 + wv * 16 + colw;
    f32x4 acc0 = {0.f, 0.f, 0.f, 0.f}, acc1 = {0.f, 0.f, 0.f, 0.f};
#pragma unroll
    for (int kt = 0; kt < 8; kt++) {
        short8 b = *(const short8*)&PB[((((size_t)kt << 12) + n) * 4 + q) * 8];
        short8 a0 = *(const short8*)&As[colw * 264 + kt * 32 + q * 8];
        short8 a1 = *(const short8*)&As[(16 + colw) * 264 + kt * 32 + q * 8];
        acc0 = __builtin_amdgcn_mfma_f32_16x16x32_bf16(a0, b, acc0, 0, 0, 0);
        acc1 = __builtin_amdgcn_mfma_f32_16x16x32_bf16(a1, b, acc1, 0, 0, 0);
    }
    const float bj = ldf(pim_b, n, f32);
#pragma unroll
    for (int half = 0; half < 2; half++) {
        const f32x4& acc = half ? acc1 : acc0;
        float sv[4], uv[4];
#pragma unroll
        for (int r = 0; r < 4; r++) {
            int row = m0 + half * 16 + q * 4 + r;
            float z = acc[r] + bj;
            int mm = mask[(size_t)row * 4096 + n];
            float ev = __expf(z);
            sv[r] = mm ? ev : 0.f;
            uv[r] = mm ? ev * z : 0.f;
            if (n == a_taken[row]) za[row] = z;
        }
#pragma unroll
        for (int r = 0; r < 4; r++) {
            for (int off = 1; off < 16; off <<= 1) {
                sv[r] += __shfl_xor(sv[r], off, 16);
                uv[r] += __shfl_xor(uv[r], off, 16);
            }
            if (colw == 0) {
                redS[wv][half * 16 + q * 4 + r] = sv[r];
                redU[wv][half * 16 + q * 4 + r] = uv[r];
            }
        }
    }
    __syncthreads();
    if (tid < 32) {
        float S = redS[0][tid] + redS[1][tid] + redS[2][tid] + redS[3][tid];
        float U = redU[0][tid] + redU[1][tid] + redU[2][tid] + redU[3][tid];
        partS[(size_t)(m0 + tid) * 64 + nb] = S;
        partU[(size_t)(m0 + tid) * 64 + nb] = U;
    }
}

// ================= K6: tail = pimfin + gae + pg + vf + fin (ticket) =========
#define TAIL_BLOCKS (16 + 256)
__global__ __launch_bounds__(256) void tail_kernel(
    const float* __restrict__ partS, const float* __restrict__ partU,
    const float* __restrict__ za,
    const float* __restrict__ entpir, const float* __restrict__ ppira,
    const float* __restrict__ vpred,
    const void* __restrict__ lgold, const void* __restrict__ gae,
    const void* __restrict__ ovp, const void* __restrict__ ret,
    float* __restrict__ scal, const int* __restrict__ flag,
    void* __restrict__ out)
{
    const int bid = blockIdx.x, tid = threadIdx.x;
    const int f32 = *flag;
    __shared__ float sh[8];
    __shared__ float mst[2];
    if (bid < 16) {
        const int r = bid * 256 + tid;
        float S = 0.f, U = 0.f;
#pragma unroll
        for (int t2 = 0; t2 < 64; t2++) {
            S += partS[(size_t)r * 64 + t2];
            U += partU[(size_t)r * 64 + t2];
        }
        float entpim = logf(S) - U / S;
        float ppima = __expf(za[r]) / S;
        float s = 0.f, s2 = 0.f;
        if (f32) {
            const float* gp = (const float*)gae;
            for (int i = tid; i < BT; i += 256) { float v = gp[i]; s += v; s2 += v * v; }
        } else {
            const u16* gp = (const u16*)gae;
            for (int i = tid; i < BT; i += 256) { float v = bf(gp[i]); s += v; s2 += v * v; }
        }
        for (int off = 32; off; off >>= 1) {
            s += __shfl_down(s, off, 64); s2 += __shfl_down(s2, off, 64);
        }
        if ((tid & 63) == 0) { sh[tid >> 6] = s; sh[4 + (tid >> 6)] = s2; }
        __syncthreads();
        if (tid == 0) {
            float Sa = sh[0] + sh[1] + sh[2] + sh[3];
            float S2a = sh[4] + sh[5] + sh[6] + sh[7];
            float mean = Sa / (float)BT;
            float var = S2a / (float)BT - mean * mean;
            mst[0] = mean; mst[1] = sqrtf(fmaxf(var, 0.f));
        }
        __syncthreads();
        float mean = mst[0], sd = mst[1];
        float p = (r & 1) ? ppima : ppira[r];
        float ln = logf(p);
        float rt = __expf(ln - ldf(lgold, r, f32));
        float g = (ldf(gae, r, f32) - mean) / (sd + 1e-8f);
        float rtc = fminf(fmaxf(rt, 0.8f), 1.2f);
        float pg = fmaxf(-g * rt, -g * rtc);
        float e12 = entpir[r] + entpim;
        for (int off = 32; off; off >>= 1) {
            pg += __shfl_down(pg, off, 64);
            e12 += __shfl_down(e12, off, 64);
        }
        if ((tid & 63) == 0) {
            atomicAdd(&scal[2], pg);
            atomicAdd(&scal[3], e12);
        }
    } else {
        const int i0 = (bid - 16) * 16;
        float s = 0.f;
        if (f32) {
            const float* rp = (const float*)ret;
            const float* op = (const float*)ovp;
            for (int rr = 0; rr < 16; rr++) {
                float vp = vpred[i0 + rr];
                for (int j = tid; j < BT; j += 256) {
                    float r2 = rp[j], o = op[j];
                    float d = fminf(fmaxf(vp - o, -0.2f), 0.2f);
                    float v1 = vp - r2;    v1 *= v1;
                    float v2 = o + d - r2; v2 *= v2;
                    s += fmaxf(v1, v2);
                }
            }
        } else {
            const u16* rp = (const u16*)ret;
            const u16* op = (const u16*)ovp;
            for (int rr = 0; rr < 16; rr++) {
                float vp = vpred[i0 + rr];
                for (int j = tid; j < BT; j += 256) {
                    float r2 = bf(rp[j]), o = bf(op[j]);
                    float d = fminf(fmaxf(vp - o, -0.2f), 0.2f);
                    float v1 = vp - r2;    v1 *= v1;
                    float v2 = o + d - r2; v2 *= v2;
                    s += fmaxf(v1, v2);
                }
            }
        }
        for (int off = 32; off; off >>= 1) s += __shfl_down(s, off, 64);
        if ((tid & 63) == 0) sh[tid >> 6] = s;
        __syncthreads();
        if (tid == 0) atomicAdd(&scal[5], sh[0] + sh[1] + sh[2] + sh[3]);
    }
    __threadfence();
    __syncthreads();
    if (tid == 0) {
        unsigned old = atomicAdd((unsigned int*)&scal[8], 1u);
        if (old == TAIL_BLOCKS - 1) {
            __threadfence();
            float pgs = atomicAdd(&scal[2], 0.f);
            float ents = atomicAdd(&scal[3], 0.f);
            float vfs = atomicAdd(&scal[5], 0.f);
            float pg = pgs / (float)BT;
            float vf = 0.5f * vfs / ((float)BT * (float)BT);
            float loss = pg - ents + vf;
            if (f32) {
                float* o = (float*)out;
                o[0] = loss; o[1] = pg; o[2] = ents; o[3] = vf;
            } else {
                u16* o = (u16*)out;
                o[0] = f2b(loss); o[1] = f2b(pg); o[2] = f2b(ents); o[3] = f2b(vf);
            }
        }
    }
}

extern "C" void kernel_launch(void* const* d_in, const int* in_sizes, int n_in,
                              void* d_out, int out_size, void* d_ws, size_t ws_size,
                              hipStream_t stream)
{
    const int* mask = (const int*)d_in[1];
    const int* a_tk = (const int*)d_in[3];

    float* p = (float*)d_ws;
    u16*   featbf = (u16*)p;            p += 524288;    // 1M u16
    float* zx     = p;                  p += 4194304;   // 16 MB
    u16*   hseqbf = (u16*)p;            p += 524288;    // 1M u16
    u16*   PF     = (u16*)p;            p += 131072;    // f16 Wr
    u16*   PBk    = (u16*)p;            p += 131072;    // bf16 Wk frag
    u16*   PBpim  = (u16*)p;            p += 524288;    // bf16 pimW frag
    u16*   PBpir  = (u16*)p;            p += 8192;      // bf16 [pirW|vW] frag
    float* scal   = p;                  p += 32;
    int*   flag   = (int*)p;            p += 4;
    float* partS  = p;                  p += 262144;
    float* partU  = p;                  p += 262144;
    float* za     = p;                  p += 4096;
    float* entpir = p;                  p += 4096;
    float* ppira  = p;                  p += 4096;
    float* vpred  = p;                  p += 4096;

    PrepPtrs P;
    P.x = d_in[0];
    P.W1 = d_in[7];  P.b1 = d_in[8];
    P.W2 = d_in[9];  P.b2 = d_in[10];
    P.W3 = d_in[11]; P.b3 = d_in[12];
    P.W4 = d_in[13]; P.b4 = d_in[14];
    P.Wk = d_in[15]; P.Wr = d_in[16];
    P.Wpir = d_in[18]; P.Wpim = d_in[20]; P.Wv = d_in[22];
    P.probe = (const u16*)d_in[15];
    P.featbf = featbf; P.PF = PF; P.PBk = PBk; P.PBpim = PBpim; P.PBpir = PBpir;
    P.scal = scal; P.flag = flag;

    prep_kernel<<<PACK_BLKS + CONV_BLKS, 256, 0, stream>>>(P);
    gemm_zx<<<dim3(16, 256), 256, 0, stream>>>(featbf, PBk, d_in[17], flag, zx);
    lstm_kernel<<<NB, 512, 0, stream>>>(zx, PF, hseqbf);
    pir_kernel<<<64, 256, 0, stream>>>(hseqbf, PBpir, d_in[19], d_in[23], flag,
                                       a_tk, entpir, ppira, vpred);
    pim_kernel<<<dim3(64, 128), 256, 0, stream>>>(hseqbf, PBpim, d_in[21], flag,
                                                  mask, a_tk, partS, partU, za);
    tail_kernel<<<TAIL_BLOCKS, 256, 0, stream>>>(
        partS, partU, za, entpir, ppira, vpred,
        d_in[2], d_in[4], d_in[5], d_in[6], scal, flag, (void*)d_out);
}

// Round 5
// 426.988 us; speedup vs baseline: 2.4582x; 1.0550x over previous
//
#include <hip/hip_runtime.h>

typedef unsigned short u16;
typedef unsigned int   u32;

#define BT   4096
#define TSEQ 64
#define NB   64

typedef __attribute__((ext_vector_type(8))) short  short8;
typedef __attribute__((ext_vector_type(4))) float  f32x4;
typedef __attribute__((ext_vector_type(4))) int    i32x4;
typedef __attribute__((ext_vector_type(2))) _Float16 h2;

__device__ __forceinline__ float bf(u16 v) {
    u32 u = ((u32)v) << 16;
    return __builtin_bit_cast(float, u);
}
__device__ __forceinline__ u16 f2b(float f) {
    u32 u = __builtin_bit_cast(u32, f);
    return (u16)((u + 0x7fffu + ((u >> 16) & 1u)) >> 16);  // RNE
}
__device__ __forceinline__ float lrelu(float x) { return x > 0.f ? x : 0.2f * x; }
__device__ __forceinline__ h2 i2h(int v) { return __builtin_bit_cast(h2, v); }
__device__ __forceinline__ float dot2(int hbits, int wbits, float acc) {
#if __has_builtin(__builtin_amdgcn_fdot2)
    return __builtin_amdgcn_fdot2(i2h(hbits), i2h(wbits), acc, false);
#else
    h2 a = i2h(hbits), b = i2h(wbits);
    return acc + (float)a.x * (float)b.x + (float)a.y * (float)b.y;
#endif
}
__device__ __forceinline__ float fsigm(float x) { return 1.f / (1.f + __expf(-x)); }
__device__ __forceinline__ float ftanh(float x) { return 1.f - 2.f / (__expf(2.f * x) + 1.f); }
__device__ __forceinline__ float ldf(const void* p, int i, int f32) {
    return f32 ? ((const float*)p)[i] : bf(((const u16*)p)[i]);
}
__device__ __forceinline__ u16 ldb(const void* p, int i, int f32) {
    return f32 ? f2b(((const float*)p)[i]) : ((const u16*)p)[i];
}

// opaque 4x16B global load: asm-defined values cannot be rematerialized, so
// the register allocator must keep them resident (or scratch-spill: tripwire).
__device__ __forceinline__ void gload4x4(const void* p0, const void* p1,
                                         const void* p2, const void* p3,
                                         i32x4& r0, i32x4& r1, i32x4& r2, i32x4& r3)
{
    asm volatile("global_load_dwordx4 %0, %4, off\n\t"
                 "global_load_dwordx4 %1, %5, off\n\t"
                 "global_load_dwordx4 %2, %6, off\n\t"
                 "global_load_dwordx4 %3, %7, off\n\t"
                 "s_waitcnt vmcnt(0)"
                 : "=&v"(r0), "=&v"(r1), "=&v"(r2), "=&v"(r3)
                 : "v"(p0), "v"(p1), "v"(p2), "v"(p3)
                 : "memory");
}

struct PrepPtrs {
    const void *x, *W1, *b1, *W2, *b2, *W3, *b3, *W4, *b4;
    const void *Wr, *Wk, *Wpim, *Wpir, *Wv;
    const u16* probe;
    u16 *featbf, *PF, *PBk, *PBpim, *PBpir;
    float* scal; int* flag;
};

// pack: each thread packs 8 consecutive k (one octet) for one column ->
// 8 coalesced reads + one contiguous 16B store (old: 2B scatter, ~16x WA)
#define PACK_BLKS 776   // PF 128 | PBk 128 | PBpim 512 | PBpir 8
#define CONV_BLKS 2048  // 2 images per block

// ================= K1: prep = sniff(inline) + pack + conv ===================
__global__ __launch_bounds__(256) void prep_kernel(PrepPtrs P)
{
    const int bid = blockIdx.x, tid = threadIdx.x;
    const int lane = tid & 63;
    u16 pv = P.probe[2 * lane];
    int e = (pv >> 7) & 0xFF;
    unsigned long long m = __ballot(pv == 0 || (e >= 100 && e <= 130));
    const int f32 = (__popcll(m) < 48) ? 1 : 0;

    if (bid == 0 && tid < 32) { P.scal[tid] = 0.f; if (tid == 0) *P.flag = f32; }

    if (bid < PACK_BLKS) {
        u16 t8[8];
        if (bid < 128) {                       // PF: Wr -> f16 chunks
            int gid = bid * 256 + tid;         // 32768: (oct, col)
            int col = gid & 1023, oct = gid >> 10;
#pragma unroll
            for (int j = 0; j < 8; j++) {
                float f = ldf(P.Wr, (oct * 8 + j) * 1024 + col, f32);
                _Float16 h = (_Float16)f;
                t8[j] = __builtin_bit_cast(unsigned short, h);
            }
            *(int4*)&P.PF[((size_t)oct * 1024 + col) * 8] = *(int4*)t8;
        } else if (bid < 256) {                // PBk: bf16 B-frag
            int gid = (bid - 128) * 256 + tid;
            int col = gid & 1023, oct = gid >> 10;
#pragma unroll
            for (int j = 0; j < 8; j++) t8[j] = ldb(P.Wk, (oct * 8 + j) * 1024 + col, f32);
            *(int4*)&P.PBk[((((size_t)(oct >> 2) << 10) + col) * 4 + (oct & 3)) * 8] = *(int4*)t8;
        } else if (bid < 768) {                // PBpim
            int gid = (bid - 256) * 256 + tid; // 131072: (oct, col)
            int col = gid & 4095, oct = gid >> 12;
#pragma unroll
            for (int j = 0; j < 8; j++) t8[j] = ldb(P.Wpim, (size_t)(oct * 8 + j) * 4096 + col, f32);
            *(int4*)&P.PBpim[((((size_t)(oct >> 2) << 12) + col) * 4 + (oct & 3)) * 8] = *(int4*)t8;
        } else {                               // PBpir: [pirW|vW|0]
            int gid = (bid - 768) * 256 + tid; // 2048: (oct, col)
            int col = gid & 63, oct = gid >> 6;
#pragma unroll
            for (int j = 0; j < 8; j++) {
                int k = oct * 8 + j;
                u16 v = 0;
                if (col < 36)       v = ldb(P.Wpir, k * 36 + col, f32);
                else if (col == 36) v = ldb(P.Wv, k, f32);
                t8[j] = v;
            }
            *(int4*)&P.PBpir[(((size_t)(oct >> 2) * 64 + col) * 4 + (oct & 3)) * 8] = *(int4*)t8;
        }
        return;
    }

    // ---- conv branch: 2 images per block; LDS-staged bf16 weights ----
    __shared__ __align__(16) u16 wl[19184];
    __shared__ float xs[2][832];
    __shared__ float c1[2][384];
    __shared__ float c2[2][480];
    __shared__ float c3[2][128];
    const int pair = bid - PACK_BLKS;
    const int sub = tid >> 7, stid = tid & 127;
    const int bt = pair * 2 + sub;

    {   // vectorized staging: float4->ushort4 (f32) / int4 copy (bf16)
        const void* sp[8] = {P.W1, P.b1, P.W2, P.b2, P.W3, P.b3, P.W4, P.b4};
        const int   sn[8] = {512, 16, 2048, 32, 8192, 64, 8192, 128};
        int o = 0;
        for (int s = 0; s < 8; s++) {
            if (f32) {
                const float4* src = (const float4*)sp[s];
                for (int i = tid; i < (sn[s] >> 2); i += 256) {
                    float4 v = src[i];
                    ushort4 w;
                    w.x = f2b(v.x); w.y = f2b(v.y); w.z = f2b(v.z); w.w = f2b(v.w);
                    *(ushort4*)&wl[o + i * 4] = w;
                }
            } else {
                const int4* src = (const int4*)sp[s];
                for (int i = tid; i < (sn[s] >> 3); i += 256)
                    *(int4*)&wl[o + i * 8] = src[i];
            }
            o += sn[s];
        }
    }
    for (int i = stid; i < 832; i += 128) xs[sub][i] = ldf(P.x, bt * 832 + i, f32);
    __syncthreads();

    for (int idx = stid; idx < 96; idx += 128) {
        int pos = idx >> 2, g = idx & 3;
        int oh = pos >> 2, ow = pos & 3;
        float a0 = bf(wl[512 + g * 4]), a1 = bf(wl[513 + g * 4]),
              a2 = bf(wl[514 + g * 4]), a3 = bf(wl[515 + g * 4]);
        for (int kh = 0; kh < 2; kh++)
            for (int kw = 0; kw < 2; kw++)
#pragma unroll
                for (int ic = 0; ic < 8; ic++) {
                    float xv = xs[sub][(2 * oh + kh) * 64 + (2 * ow + kw) * 8 + ic];
                    ushort4 w = *(const ushort4*)&wl[((kh * 2 + kw) * 8 + ic) * 16 + g * 4];
                    a0 += xv * bf(w.x); a1 += xv * bf(w.y);
                    a2 += xv * bf(w.z); a3 += xv * bf(w.w);
                }
        c1[sub][pos * 16 + g * 4]     = lrelu(a0);
        c1[sub][pos * 16 + g * 4 + 1] = lrelu(a1);
        c1[sub][pos * 16 + g * 4 + 2] = lrelu(a2);
        c1[sub][pos * 16 + g * 4 + 3] = lrelu(a3);
    }
    __syncthreads();

    for (int idx = stid; idx < 120; idx += 128) {
        int pos = idx >> 3, g = idx & 7;
        int oh = pos / 3, ow = pos % 3;
        float a0 = bf(wl[2576 + g * 4]), a1 = bf(wl[2577 + g * 4]),
              a2 = bf(wl[2578 + g * 4]), a3 = bf(wl[2579 + g * 4]);
        for (int kh = 0; kh < 2; kh++)
            for (int kw = 0; kw < 2; kw++)
#pragma unroll
                for (int ic = 0; ic < 16; ic++) {
                    float xv = c1[sub][((oh + kh) * 4 + (ow + kw)) * 16 + ic];
                    ushort4 w = *(const ushort4*)&wl[528 + ((kh * 2 + kw) * 16 + ic) * 32 + g * 4];
                    a0 += xv * bf(w.x); a1 += xv * bf(w.y);
                    a2 += xv * bf(w.z); a3 += xv * bf(w.w);
                }
        c2[sub][pos * 32 + g * 4]     = lrelu(a0);
        c2[sub][pos * 32 + g * 4 + 1] = lrelu(a1);
        c2[sub][pos * 32 + g * 4 + 2] = lrelu(a2);
        c2[sub][pos * 32 + g * 4 + 3] = lrelu(a3);
    }
    __syncthreads();

    for (int idx = stid; idx < 32; idx += 128) {
        int oh = idx >> 4, g = idx & 15;
        float a0 = bf(wl[10800 + g * 4]), a1 = bf(wl[10801 + g * 4]),
              a2 = bf(wl[10802 + g * 4]), a3 = bf(wl[10803 + g * 4]);
        for (int kh = 0; kh < 2; kh++)
            for (int kw = 0; kw < 2; kw++)
#pragma unroll
                for (int ic = 0; ic < 32; ic++) {
                    float xv = c2[sub][((2 * oh + kh) * 3 + kw) * 32 + ic];
                    ushort4 w = *(const ushort4*)&wl[2608 + ((kh * 2 + kw) * 32 + ic) * 64 + g * 4];
                    a0 += xv * bf(w.x); a1 += xv * bf(w.y);
                    a2 += xv * bf(w.z); a3 += xv * bf(w.w);
                }
        c3[sub][oh * 64 + g * 4]     = lrelu(a0);
        c3[sub][oh * 64 + g * 4 + 1] = lrelu(a1);
        c3[sub][oh * 64 + g * 4 + 2] = lrelu(a2);
        c3[sub][oh * 64 + g * 4 + 3] = lrelu(a3);
    }
    __syncthreads();

    for (int idx = stid; idx < 64; idx += 128) {
        int oh = idx >> 5, g = idx & 31;
        float a0 = bf(wl[19056 + g * 4]), a1 = bf(wl[19057 + g * 4]),
              a2 = bf(wl[19058 + g * 4]), a3 = bf(wl[19059 + g * 4]);
#pragma unroll
        for (int ic = 0; ic < 64; ic++) {
            float xv = c3[sub][oh * 64 + ic];
            ushort4 w = *(const ushort4*)&wl[10864 + ic * 128 + g * 4];
            a0 += xv * bf(w.x); a1 += xv * bf(w.y);
            a2 += xv * bf(w.z); a3 += xv * bf(w.w);
        }
        P.featbf[bt * 256 + (g * 4 + 0) * 2 + oh] = f2b(lrelu(a0));
        P.featbf[bt * 256 + (g * 4 + 1) * 2 + oh] = f2b(lrelu(a1));
        P.featbf[bt * 256 + (g * 4 + 2) * 2 + oh] = f2b(lrelu(a2));
        P.featbf[bt * 256 + (g * 4 + 3) * 2 + oh] = f2b(lrelu(a3));
    }
}

// ================= K2: zx = featbf @ Wk + b (MFMA) ==========================
__global__ __launch_bounds__(256) void gemm_zx(
    const u16* __restrict__ Abf, const u16* __restrict__ PB,
    const void* __restrict__ bias, const int* __restrict__ flag,
    float* __restrict__ out)
{
    __shared__ __align__(16) u16 As[16 * 264];
    const int mb = blockIdx.y, nb = blockIdx.x, tid = threadIdx.x;
    const int f32 = *flag;
    const int m0 = mb * 16;
    {
        int row = tid >> 4, part = tid & 15;
        const f32x4* src = (const f32x4*)&Abf[(size_t)(m0 + row) * 256 + part * 16];
        f32x4 v0 = src[0], v1 = src[1];
        *(f32x4*)&As[row * 264 + part * 16] = v0;
        *(f32x4*)&As[row * 264 + part * 16 + 8] = v1;
    }
    __syncthreads();
    const int wv = tid >> 6, lane = tid & 63;
    const int colw = lane & 15, q = lane >> 4;
    const int n = nb * 64 + wv * 16 + colw;
    f32x4 acc = {0.f, 0.f, 0.f, 0.f};
#pragma unroll
    for (int kt = 0; kt < 8; kt++) {
        short8 a = *(const short8*)&As[colw * 264 + kt * 32 + q * 8];
        short8 b = *(const short8*)&PB[((((size_t)kt << 10) + n) * 4 + q) * 8];
        acc = __builtin_amdgcn_mfma_f32_16x16x32_bf16(a, b, acc, 0, 0, 0);
    }
    const float bj = ldf(bias, n, f32);
#pragma unroll
    for (int r = 0; r < 4; r++) {
        int row = q * 4 + r;
        out[(size_t)(m0 + row) * 1024 + n] = acc[r] + bj;
    }
}

// ================= K3: LSTM — readlane h-broadcast, asm-loaded weights ======
// 64 blocks (1/seq) x 512 threads. Thread (c = tid&255, kh = tid>>8) does
// K in [128kh,128kh+128) for gate columns {g*256+c}. ROUND-4 LESSON: the DS
// pipe was the floor (256 ds_read_b128/step/CU ~ 3k cy), not weight
// residency. Fix: ONE lane-varying ds_read_b128/wave pulls the wave's whole
// K-half of h (lane l holds half-octet l&15, 4-way dup), distributed via
// v_readlane (VALU pipe) -> DS drops to ~150 instrs/step (128 wlds reads
// irreducible). Weights: 12 octets via opaque asm global_load (remat-proof,
// ~225 arch VGPRs) + 4 octets in LDS (128 KB).
#define NREG 12
#define NLDS4 4
__global__ __launch_bounds__(512)
__attribute__((amdgpu_waves_per_eu(2, 2)))
void lstm_kernel(
    const float* __restrict__ zx, const u16* __restrict__ PF,
    u16* __restrict__ hseqbf)
{
    __shared__ __align__(16) u16 h16[264];                     // h(t), f16
    __shared__ __align__(16) float zp[2048];                   // [kh][c][g]
    __shared__ __align__(16) int4 wlds[2][NLDS4][4][256];      // 128 KB
    const int b = blockIdx.x, tid = threadIdx.x;
    const int c = tid & 255, kh = tid >> 8;

    // pinned weights: octets kh*16+0..11, all 4 gates (asm def -> no remat)
    i32x4 wr[NREG][4];
#pragma unroll
    for (int o = 0; o < NREG; o++) {
        const u16* p0 = &PF[((size_t)(kh * 16 + o) * 1024 + 0 * 256 + c) * 8];
        const u16* p1 = &PF[((size_t)(kh * 16 + o) * 1024 + 1 * 256 + c) * 8];
        const u16* p2 = &PF[((size_t)(kh * 16 + o) * 1024 + 2 * 256 + c) * 8];
        const u16* p3 = &PF[((size_t)(kh * 16 + o) * 1024 + 3 * 256 + c) * 8];
        gload4x4(p0, p1, p2, p3, wr[o][0], wr[o][1], wr[o][2], wr[o][3]);
    }
    // LDS-resident: octets kh*16+12..15
    {
        const int4* Pw = (const int4*)PF;
#pragma unroll
        for (int o = 0; o < NLDS4; o++)
#pragma unroll
            for (int g = 0; g < 4; g++)
                wlds[kh][o][g][c] = Pw[(size_t)(kh * 16 + NREG + o) * 1024 + g * 256 + c];
    }

    if (tid < 132) ((u32*)h16)[tid] = 0u;
    float cst = 0.f;
    const size_t z0 = (size_t)b * TSEQ * 1024;
    float zxv0 = 0.f, zxv1 = 0.f, zxv2 = 0.f, zxv3 = 0.f;
    if (tid < 256) {
        zxv0 = zx[z0 + c];       zxv1 = zx[z0 + 256 + c];
        zxv2 = zx[z0 + 512 + c]; zxv3 = zx[z0 + 768 + c];
    }
    __syncthreads();

    for (int t = 0; t < TSEQ; t++) {
        // one lane-varying read: lane l holds half-octet (l&15) of this K-half
        int4 vh = *(const int4*)&h16[(kh * 16 + (tid & 15)) * 8];
        float a0 = 0.f, a1 = 0.f, a2 = 0.f, a3 = 0.f;
#pragma unroll
        for (int j = 0; j < NREG; j++) {
            int h0 = __builtin_amdgcn_readlane(vh.x, j);
            int h1 = __builtin_amdgcn_readlane(vh.y, j);
            int h2 = __builtin_amdgcn_readlane(vh.z, j);
            int h3 = __builtin_amdgcn_readlane(vh.w, j);
            a0 = dot2(h0, wr[j][0].x, a0); a0 = dot2(h1, wr[j][0].y, a0);
            a0 = dot2(h2, wr[j][0].z, a0); a0 = dot2(h3, wr[j][0].w, a0);
            a1 = dot2(h0, wr[j][1].x, a1); a1 = dot2(h1, wr[j][1].y, a1);
            a1 = dot2(h2, wr[j][1].z, a1); a1 = dot2(h3, wr[j][1].w, a1);
            a2 = dot2(h0, wr[j][2].x, a2); a2 = dot2(h1, wr[j][2].y, a2);
            a2 = dot2(h2, wr[j][2].z, a2); a2 = dot2(h3, wr[j][2].w, a2);
            a3 = dot2(h0, wr[j][3].x, a3); a3 = dot2(h1, wr[j][3].y, a3);
            a3 = dot2(h2, wr[j][3].z, a3); a3 = dot2(h3, wr[j][3].w, a3);
        }
#pragma unroll
        for (int jj = 0; jj < NLDS4; jj++) {
            const int j = NREG + jj;
            int4 w0 = wlds[kh][jj][0][c];
            int4 w1 = wlds[kh][jj][1][c];
            int4 w2 = wlds[kh][jj][2][c];
            int4 w3 = wlds[kh][jj][3][c];
            int h0 = __builtin_amdgcn_readlane(vh.x, j);
            int h1 = __builtin_amdgcn_readlane(vh.y, j);
            int h2 = __builtin_amdgcn_readlane(vh.z, j);
            int h3 = __builtin_amdgcn_readlane(vh.w, j);
            a0 = dot2(h0, w0.x, a0); a0 = dot2(h1, w0.y, a0);
            a0 = dot2(h2, w0.z, a0); a0 = dot2(h3, w0.w, a0);
            a1 = dot2(h0, w1.x, a1); a1 = dot2(h1, w1.y, a1);
            a1 = dot2(h2, w1.z, a1); a1 = dot2(h3, w1.w, a1);
            a2 = dot2(h0, w2.x, a2); a2 = dot2(h1, w2.y, a2);
            a2 = dot2(h2, w2.z, a2); a2 = dot2(h3, w2.w, a2);
            a3 = dot2(h0, w3.x, a3); a3 = dot2(h1, w3.y, a3);
            a3 = dot2(h2, w3.z, a3); a3 = dot2(h3, w3.w, a3);
        }
        *(f32x4*)&zp[((kh << 8) + c) * 4] = (f32x4){a0, a1, a2, a3};
        __syncthreads();

        if (tid < 256) {
            f32x4 s0 = *(const f32x4*)&zp[c * 4];
            f32x4 s1 = *(const f32x4*)&zp[1024 + c * 4];
            float zi = s0.x + s1.x + zxv0;
            float zf = s0.y + s1.y + zxv1;
            float zg = s0.z + s1.z + zxv2;
            float zo = s0.w + s1.w + zxv3;
            // prefetch next-step zx (consumed a full step later)
            if (t + 1 < TSEQ) {
                const size_t zr = z0 + (size_t)(t + 1) * 1024;
                zxv0 = zx[zr + c];       zxv1 = zx[zr + 256 + c];
                zxv2 = zx[zr + 512 + c]; zxv3 = zx[zr + 768 + c];
            }
            float ig = fsigm(zi), fg = fsigm(zf), og = fsigm(zo);
            float gg = ftanh(zg);
            cst = fg * cst + ig * gg;
            float h = og * ftanh(cst);
            h16[c] = __builtin_bit_cast(unsigned short, (_Float16)h);
            hseqbf[(size_t)b * (TSEQ * 256) + t * 256 + c] = f2b(h);
        }
        __syncthreads();
    }
}

// ================= K4: pir head + vpred (64 blocks) =========================
__global__ __launch_bounds__(256) void pir_kernel(
    const u16* __restrict__ Abf, const u16* __restrict__ PB,
    const void* __restrict__ pir_b, const void* __restrict__ v_b,
    const int* __restrict__ flag, const int* __restrict__ a_taken,
    float* __restrict__ entpir, float* __restrict__ ppira, float* __restrict__ vpred)
{
    __shared__ __align__(16) u16 As[64 * 264];
    const int tid = threadIdx.x;
    const int wv = tid >> 6, lane = tid & 63;
    const int colw = lane & 15, q = lane >> 4;
    const int f32 = *flag;
    const int m0 = blockIdx.x * 64;

    for (int idx = tid; idx < 1024; idx += 256) {
        int row = idx >> 4, part = idx & 15;
        const f32x4* src = (const f32x4*)&Abf[(size_t)(m0 + row) * 256 + part * 16];
        f32x4 v0 = src[0], v1 = src[1];
        *(f32x4*)&As[row * 264 + part * 16] = v0;
        *(f32x4*)&As[row * 264 + part * 16 + 8] = v1;
    }
    __syncthreads();
    f32x4 acc[4];
#pragma unroll
    for (int nt = 0; nt < 4; nt++) acc[nt] = (f32x4){0.f, 0.f, 0.f, 0.f};
#pragma unroll
    for (int kt = 0; kt < 8; kt++) {
        short8 a = *(const short8*)&As[(wv * 16 + colw) * 264 + kt * 32 + q * 8];
#pragma unroll
        for (int nt = 0; nt < 4; nt++) {
            short8 b = *(const short8*)&PB[((((size_t)kt * 64) + nt * 16 + colw) * 4 + q) * 8];
            acc[nt] = __builtin_amdgcn_mfma_f32_16x16x32_bf16(a, b, acc[nt], 0, 0, 0);
        }
    }
    float* zq = (float*)&As[wv * 4224];   // wave-local 16x65 overlay
#pragma unroll
    for (int nt = 0; nt < 4; nt++) {
        int col = nt * 16 + colw;
        float bj = (col < 36) ? ldf(pir_b, col, f32)
                              : (col == 36 ? ldf(v_b, 0, f32) : 0.f);
#pragma unroll
        for (int r = 0; r < 4; r++)
            zq[(q * 4 + r) * 65 + col] = acc[nt][r] + bj;
    }
    if (lane < 16) {
        int R = m0 + wv * 16 + lane;
        const float* zrow = &zq[lane * 65];
        float Z = 0.f, U = 0.f;
        for (int cc = 0; cc < 36; cc++) {
            float z = zrow[cc];
            float ev = __expf(z);
            Z += ev; U += ev * z;
        }
        entpir[R] = logf(Z) - U / Z;
        ppira[R]  = __expf(zrow[a_taken[R]]) / Z;
        vpred[R]  = zrow[36];
    }
}

// ================= K5: pim — M=32 tiles, fused masked-softmax partials ======
__global__ __launch_bounds__(256) void pim_kernel(
    const u16* __restrict__ Abf, const u16* __restrict__ PB,
    const void* __restrict__ pim_b, const int* __restrict__ flag,
    const int* __restrict__ mask, const int* __restrict__ a_taken,
    float* __restrict__ partS, float* __restrict__ partU, float* __restrict__ za)
{
    __shared__ __align__(16) u16 As[32 * 264];   // 16.9 KB
    __shared__ float redS[4][32], redU[4][32];
    const int nb = blockIdx.x, mb = blockIdx.y, tid = threadIdx.x;
    const int wv = tid >> 6, lane = tid & 63;
    const int colw = lane & 15, q = lane >> 4;
    const int f32 = *flag;
    const int m0 = mb * 32;

    for (int idx = tid; idx < 512; idx += 256) {
        int row = idx >> 4, part = idx & 15;
        const f32x4* src = (const f32x4*)&Abf[(size_t)(m0 + row) * 256 + part * 16];
        f32x4 v0 = src[0], v1 = src[1];
        *(f32x4*)&As[row * 264 + part * 16] = v0;
        *(f32x4*)&As[row * 264 + part * 16 + 8] = v1;
    }
    __syncthreads();
    const int n = nb * 64 + wv * 16 + colw;
    f32x4 acc0 = {0.f, 0.f, 0.f, 0.f}, acc1 = {0.f, 0.f, 0.f, 0.f};
#pragma unroll
    for (int kt = 0; kt < 8; kt++) {
        short8 b = *(const short8*)&PB[((((size_t)kt << 12) + n) * 4 + q) * 8];
        short8 a0 = *(const short8*)&As[colw * 264 + kt * 32 + q * 8];
        short8 a1 = *(const short8*)&As[(16 + colw) * 264 + kt * 32 + q * 8];
        acc0 = __builtin_amdgcn_mfma_f32_16x16x32_bf16(a0, b, acc0, 0, 0, 0);
        acc1 = __builtin_amdgcn_mfma_f32_16x16x32_bf16(a1, b, acc1, 0, 0, 0);
    }
    const float bj = ldf(pim_b, n, f32);
#pragma unroll
    for (int half = 0; half < 2; half++) {
        const f32x4& acc = half ? acc1 : acc0;
        float sv[4], uv[4];
#pragma unroll
        for (int r = 0; r < 4; r++) {
            int row = m0 + half * 16 + q * 4 + r;
            float z = acc[r] + bj;
            int mm = mask[(size_t)row * 4096 + n];
            float ev = __expf(z);
            sv[r] = mm ? ev : 0.f;
            uv[r] = mm ? ev * z : 0.f;
            if (n == a_taken[row]) za[row] = z;
        }
#pragma unroll
        for (int r = 0; r < 4; r++) {
            for (int off = 1; off < 16; off <<= 1) {
                sv[r] += __shfl_xor(sv[r], off, 16);
                uv[r] += __shfl_xor(uv[r], off, 16);
            }
            if (colw == 0) {
                redS[wv][half * 16 + q * 4 + r] = sv[r];
                redU[wv][half * 16 + q * 4 + r] = uv[r];
            }
        }
    }
    __syncthreads();
    if (tid < 32) {
        float S = redS[0][tid] + redS[1][tid] + redS[2][tid] + redS[3][tid];
        float U = redU[0][tid] + redU[1][tid] + redU[2][tid] + redU[3][tid];
        partS[(size_t)(m0 + tid) * 64 + nb] = S;
        partU[(size_t)(m0 + tid) * 64 + nb] = U;
    }
}

// ================= K6: tail = pimfin + gae + pg + vf + fin (ticket) =========
#define TAIL_BLOCKS (16 + 256)
__global__ __launch_bounds__(256) void tail_kernel(
    const float* __restrict__ partS, const float* __restrict__ partU,
    const float* __restrict__ za,
    const float* __restrict__ entpir, const float* __restrict__ ppira,
    const float* __restrict__ vpred,
    const void* __restrict__ lgold, const void* __restrict__ gae,
    const void* __restrict__ ovp, const void* __restrict__ ret,
    float* __restrict__ scal, const int* __restrict__ flag,
    void* __restrict__ out)
{
    const int bid = blockIdx.x, tid = threadIdx.x;
    const int f32 = *flag;
    __shared__ float sh[8];
    __shared__ float mst[2];
    if (bid < 16) {
        const int r = bid * 256 + tid;
        float S = 0.f, U = 0.f;
#pragma unroll
        for (int t2 = 0; t2 < 64; t2++) {
            S += partS[(size_t)r * 64 + t2];
            U += partU[(size_t)r * 64 + t2];
        }
        float entpim = logf(S) - U / S;
        float ppima = __expf(za[r]) / S;
        float s = 0.f, s2 = 0.f;
        if (f32) {
            const float* gp = (const float*)gae;
            for (int i = tid; i < BT; i += 256) { float v = gp[i]; s += v; s2 += v * v; }
        } else {
            const u16* gp = (const u16*)gae;
            for (int i = tid; i < BT; i += 256) { float v = bf(gp[i]); s += v; s2 += v * v; }
        }
        for (int off = 32; off; off >>= 1) {
            s += __shfl_down(s, off, 64); s2 += __shfl_down(s2, off, 64);
        }
        if ((tid & 63) == 0) { sh[tid >> 6] = s; sh[4 + (tid >> 6)] = s2; }
        __syncthreads();
        if (tid == 0) {
            float Sa = sh[0] + sh[1] + sh[2] + sh[3];
            float S2a = sh[4] + sh[5] + sh[6] + sh[7];
            float mean = Sa / (float)BT;
            float var = S2a / (float)BT - mean * mean;
            mst[0] = mean; mst[1] = sqrtf(fmaxf(var, 0.f));
        }
        __syncthreads();
        float mean = mst[0], sd = mst[1];
        float p = (r & 1) ? ppima : ppira[r];
        float ln = logf(p);
        float rt = __expf(ln - ldf(lgold, r, f32));
        float g = (ldf(gae, r, f32) - mean) / (sd + 1e-8f);
        float rtc = fminf(fmaxf(rt, 0.8f), 1.2f);
        float pg = fmaxf(-g * rt, -g * rtc);
        float e12 = entpir[r] + entpim;
        for (int off = 32; off; off >>= 1) {
            pg += __shfl_down(pg, off, 64);
            e12 += __shfl_down(e12, off, 64);
        }
        if ((tid & 63) == 0) {
            atomicAdd(&scal[2], pg);
            atomicAdd(&scal[3], e12);
        }
    } else {
        const int i0 = (bid - 16) * 16;
        float s = 0.f;
        if (f32) {
            const float* rp = (const float*)ret;
            const float* op = (const float*)ovp;
            for (int rr = 0; rr < 16; rr++) {
                float vp = vpred[i0 + rr];
                for (int j = tid; j < BT; j += 256) {
                    float r2 = rp[j], o = op[j];
                    float d = fminf(fmaxf(vp - o, -0.2f), 0.2f);
                    float v1 = vp - r2;    v1 *= v1;
                    float v2 = o + d - r2; v2 *= v2;
                    s += fmaxf(v1, v2);
                }
            }
        } else {
            const u16* rp = (const u16*)ret;
            const u16* op = (const u16*)ovp;
            for (int rr = 0; rr < 16; rr++) {
                float vp = vpred[i0 + rr];
                for (int j = tid; j < BT; j += 256) {
                    float r2 = bf(rp[j]), o = bf(op[j]);
                    float d = fminf(fmaxf(vp - o, -0.2f), 0.2f);
                    float v1 = vp - r2;    v1 *= v1;
                    float v2 = o + d - r2; v2 *= v2;
                    s += fmaxf(v1, v2);
                }
            }
        }
        for (int off = 32; off; off >>= 1) s += __shfl_down(s, off, 64);
        if ((tid & 63) == 0) sh[tid >> 6] = s;
        __syncthreads();
        if (tid == 0) atomicAdd(&scal[5], sh[0] + sh[1] + sh[2] + sh[3]);
    }
    __threadfence();
    __syncthreads();
    if (tid == 0) {
        unsigned old = atomicAdd((unsigned int*)&scal[8], 1u);
        if (old == TAIL_BLOCKS - 1) {
            __threadfence();
            float pgs = atomicAdd(&scal[2], 0.f);
            float ents = atomicAdd(&scal[3], 0.f);
            float vfs = atomicAdd(&scal[5], 0.f);
            float pg = pgs / (float)BT;
            float vf = 0.5f * vfs / ((float)BT * (float)BT);
            float loss = pg - ents + vf;
            if (f32) {
                float* o = (float*)out;
                o[0] = loss; o[1] = pg; o[2] = ents; o[3] = vf;
            } else {
                u16* o = (u16*)out;
                o[0] = f2b(loss); o[1] = f2b(pg); o[2] = f2b(ents); o[3] = f2b(vf);
            }
        }
    }
}

extern "C" void kernel_launch(void* const* d_in, const int* in_sizes, int n_in,
                              void* d_out, int out_size, void* d_ws, size_t ws_size,
                              hipStream_t stream)
{
    const int* mask = (const int*)d_in[1];
    const int* a_tk = (const int*)d_in[3];

    float* p = (float*)d_ws;
    u16*   featbf = (u16*)p;            p += 524288;    // 1M u16
    float* zx     = p;                  p += 4194304;   // 16 MB
    u16*   hseqbf = (u16*)p;            p += 524288;    // 1M u16
    u16*   PF     = (u16*)p;            p += 131072;    // f16 Wr
    u16*   PBk    = (u16*)p;            p += 131072;    // bf16 Wk frag
    u16*   PBpim  = (u16*)p;            p += 524288;    // bf16 pimW frag
    u16*   PBpir  = (u16*)p;            p += 8192;      // bf16 [pirW|vW] frag
    float* scal   = p;                  p += 32;
    int*   flag   = (int*)p;            p += 4;
    float* partS  = p;                  p += 262144;
    float* partU  = p;                  p += 262144;
    float* za     = p;                  p += 4096;
    float* entpir = p;                  p += 4096;
    float* ppira  = p;                  p += 4096;
    float* vpred  = p;                  p += 4096;

    PrepPtrs P;
    P.x = d_in[0];
    P.W1 = d_in[7];  P.b1 = d_in[8];
    P.W2 = d_in[9];  P.b2 = d_in[10];
    P.W3 = d_in[11]; P.b3 = d_in[12];
    P.W4 = d_in[13]; P.b4 = d_in[14];
    P.Wk = d_in[15]; P.Wr = d_in[16];
    P.Wpir = d_in[18]; P.Wpim = d_in[20]; P.Wv = d_in[22];
    P.probe = (const u16*)d_in[15];
    P.featbf = featbf; P.PF = PF; P.PBk = PBk; P.PBpim = PBpim; P.PBpir = PBpir;
    P.scal = scal; P.flag = flag;

    prep_kernel<<<PACK_BLKS + CONV_BLKS, 256, 0, stream>>>(P);
    gemm_zx<<<dim3(16, 256), 256, 0, stream>>>(featbf, PBk, d_in[17], flag, zx);
    lstm_kernel<<<NB, 512, 0, stream>>>(zx, PF, hseqbf);
    pir_kernel<<<64, 256, 0, stream>>>(hseqbf, PBpir, d_in[19], d_in[23], flag,
                                       a_tk, entpir, ppira, vpred);
    pim_kernel<<<dim3(64, 128), 256, 0, stream>>>(hseqbf, PBpim, d_in[21], flag,
                                                  mask, a_tk, partS, partU, za);
    tail_kernel<<<TAIL_BLOCKS, 256, 0, stream>>>(
        partS, partU, za, entpir, ppira, vpred,
        d_in[2], d_in[4], d_in[5], d_in[6], scal, flag, (void*)d_out);
}